// Round 9
// baseline (194.961 us; speedup 1.0000x reference)
//
#include <hip/hip_runtime.h>

typedef __bf16 bf16_t;
typedef bf16_t bf16x8 __attribute__((ext_vector_type(8)));
typedef float f32x4 __attribute__((ext_vector_type(4)));

#define MFMA16(a,b,c) __builtin_amdgcn_mfma_f32_16x16x32_bf16((a),(b),(c),0,0,0)

#define GLOAD_LDS16(gsrc, ldst) \
  __builtin_amdgcn_global_load_lds((const __attribute__((address_space(1))) unsigned int*)(gsrc), \
                                   (__attribute__((address_space(3))) unsigned int*)(ldst), 16, 0, 0)

__device__ __forceinline__ unsigned cvtpk(float lo, float hi){
  unsigned r; asm("v_cvt_pk_bf16_f32 %0, %1, %2" : "=v"(r) : "v"(lo), "v"(hi)); return r;
}
__device__ __forceinline__ ushort4 pk4f(float a, float b, float c, float d){
  union { unsigned u[2]; ushort4 s; } r;
  r.u[0] = cvtpk(a, b); r.u[1] = cvtpk(c, d); return r.s;
}
__device__ __forceinline__ ushort4 pk4(f32x4 v){ return pk4f(v[0], v[1], v[2], v[3]); }
__device__ __forceinline__ float max3f(float a, float b, float c){
  float r; asm("v_max3_f32 %0, %1, %2, %3" : "=v"(r) : "v"(a), "v"(b), "v"(c)); return r;
}
__device__ __forceinline__ float bf2f(unsigned short u){
  return __builtin_bit_cast(float, (unsigned int)u << 16);
}

// KI: k-interleave within 64-elem segment (for Q/K/V consumed by attention).
__device__ __forceinline__ int KI(int d){   // d 4-aligned
  int gi = (d >> 2) & 15;
  int pos = (gi & 8) | ((gi & 3) << 1) | ((gi >> 2) & 1);
  return (d & ~63) | (pos << 2);
}

// Blocked fragment layout for GEMM operands [R][256]:
// wave fragment load at (rowbase*256 + ks*16 + lq*32 + lg*8) is contiguous 1KB.
__device__ __forceinline__ int BL256(int r, int c){
  return ((r >> 4) << 12) + (((c >> 5)) << 9) + ((r & 15) << 5)
       + (((c & 15) >> 2) << 3) + (((c >> 4) & 1) << 2) + (c & 3);
}

constexpr int BN = 2;
constexpr int CC = 256;
constexpr int S  = 4096;
constexpr int HH = 4;
constexpr int DD = 64;

constexpr size_t OFF_WQ = 0;
constexpr size_t OFF_WK = 65536;
constexpr size_t OFF_WV = 131072;
constexpr size_t OFF_WO = 196608;
constexpr size_t OFF_NY = 262144;                      // blocked [p][c]
constexpr size_t OFF_NX = OFF_NY + (size_t)BN*S*CC;    // blocked [p][c]
constexpr size_t OFF_Q  = OFF_NX + (size_t)BN*S*CC;    // [b][h][p][d~KI] (pre-scaled 0.125*log2e)
constexpr size_t OFF_K  = OFF_Q  + (size_t)BN*S*CC;    // [b][h][p][d~KI]
constexpr size_t OFF_V  = OFF_K  + (size_t)BN*S*CC;    // [b][c][p~KI]
constexpr size_t OFF_AO = OFF_V  + (size_t)BN*S*CC;    // (dead after qkv: reused as PACC ch2)
constexpr size_t WS_NEED_BYTES = (OFF_AO + (size_t)BN*S*CC) * 2;   // 25,690,112
// Attention partials (3 t-chunks): ch0->NY, ch1->NX, ch2->AO (dead after qkv_gemm).
// ML [3][8][4096][2] f32 overlays OFF_Q (clobbers Q[bh0..1.5]). SAFE: attn grid (768)
// is fully co-resident (>=3 blocks/CU enforced by __launch_bounds__(256,3)); every block
// reads Q in its prologue long before any epilogue ML write. qkv rewrites Q each call.
__device__ __forceinline__ unsigned short* pacc_base(unsigned short* ws, int ch){
  return ws + (ch == 0 ? OFF_NY : (ch == 1 ? OFF_NX : OFF_AO));
}

// ---------------- fused weight-convert + GroupNorm ----------------
__global__ __launch_bounds__(256) void prep_k(const float* __restrict__ x, const float* __restrict__ y,
    const float* __restrict__ g1, const float* __restrict__ b1,
    const float* __restrict__ g2, const float* __restrict__ b2,
    const float* __restrict__ wq, const float* __restrict__ wk,
    const float* __restrict__ wv, const float* __restrict__ wo,
    unsigned short* __restrict__ ws)
{
  __shared__ float red[8];
  __shared__ float mv[2];
  const int tid = threadIdx.x;
  const int bid = blockIdx.x;

  if (bid >= 128){
    const int idx = (bid - 128)*256 + tid;
    const int m = idx >> 14;
    const int off = (idx & 16383) << 2;
    const float* src = (m==0) ? wq : (m==1) ? wk : (m==2) ? wv : wo;
    float4 v = *(const float4*)(src + off);
    const int o = off >> 8, c = off & 255;
    *(ushort4*)(ws + (size_t)m*65536 + BL256(o, c)) = pk4f(v.x, v.y, v.z, v.w);
    return;
  }

  const int tsel = bid >> 6;
  const int rem  = bid & 63;
  const int b = rem >> 5, g = rem & 31;
  const float* in = (tsel ? y : x) + ((size_t)b*CC + g*8)*S;
  unsigned short* outp = ws + (tsel ? OFF_NY : OFF_NX) + (size_t)b*S*CC;
  const int j = g & 3;
  const int gk = (g >> 2) * 512;
  const int posA = (j & 1)*16 + (j >> 1)*4;
  const int posB = posA + 8;
  const float* gamma = (tsel ? g2 : g1) + g*8;
  const float* beta  = (tsel ? b2 : b1) + g*8;

  float s = 0.f, ss = 0.f;
  #pragma unroll
  for (int ci = 0; ci < 8; ci++){
    const float4* row = (const float4*)(in + (size_t)ci*S);
    #pragma unroll
    for (int i = 0; i < 4; i++){
      float4 v = row[tid + i*256];
      s  += v.x + v.y + v.z + v.w;
      ss += v.x*v.x + v.y*v.y + v.z*v.z + v.w*v.w;
    }
  }
  #pragma unroll
  for (int off = 1; off < 64; off <<= 1){
    s  += __shfl_xor(s,  off);
    ss += __shfl_xor(ss, off);
  }
  const int wave = tid >> 6, lane = tid & 63;
  if (lane == 0){ red[wave] = s; red[4+wave] = ss; }
  __syncthreads();
  if (tid == 0){
    float S1 = red[0]+red[1]+red[2]+red[3];
    float S2 = red[4]+red[5]+red[6]+red[7];
    const float invn = 1.0f/32768.0f;
    float mean = S1*invn;
    float var  = S2*invn - mean*mean;
    mv[0] = mean; mv[1] = rsqrtf(var + 1e-6f);
  }
  __syncthreads();
  const float mean = mv[0], rstd = mv[1];
  float sc[8], sh[8];
  #pragma unroll
  for (int ci = 0; ci < 8; ci++){ sc[ci] = rstd*gamma[ci]; sh[ci] = beta[ci] - mean*sc[ci]; }
  for (int i = 0; i < 16; i++){
    const int p = tid + i*256;
    const int base = ((p >> 4) << 12) + gk + ((p & 15) << 5);
    ushort4 a0 = pk4f(in[0*S+p]*sc[0]+sh[0], in[1*S+p]*sc[1]+sh[1],
                      in[2*S+p]*sc[2]+sh[2], in[3*S+p]*sc[3]+sh[3]);
    ushort4 a1 = pk4f(in[4*S+p]*sc[4]+sh[4], in[5*S+p]*sc[5]+sh[5],
                      in[6*S+p]*sc[6]+sh[6], in[7*S+p]*sc[7]+sh[7]);
    *(ushort4*)(outp + base + posA) = a0;
    *(ushort4*)(outp + base + posB) = a1;
  }
}

// ---------------- Q/K/V projection GEMMs, 768 blocks (3/CU) ----------------
__global__ __launch_bounds__(256, 3) void qkv_gemm(unsigned short* __restrict__ ws,
    const float* __restrict__ bq, const float* __restrict__ bk, const float* __restrict__ bv)
{
  const int tid = threadIdx.x;
  const int lane = tid & 63, wave = tid >> 6;
  const int lq = lane & 15, lg = lane >> 4;
  const int lofs = lq*32 + lg*8;
  const int bid = blockIdx.x;

  if (bid < 512){
    const int inst2 = bid >> 7;             // 0..3
    const int which = inst2 >> 1;           // 0=Q,1=K
    const int b = inst2 & 1;
    const int tile = bid & 127;
    const int mtile = tile & 3;
    const int ntile = tile >> 2;
    const int mbase = mtile*64 + (wave>>1)*32;
    const int nbase = ntile*128 + (wave&1)*64;
    const unsigned short* Amat = ws + (which==0 ? OFF_WQ : OFF_WK);
    const unsigned short* Bmat = ws + (which==0 ? OFF_NY : OFF_NX) + (size_t)b*S*CC;

    f32x4 acc[2][4];
    #pragma unroll
    for (int i = 0; i < 2; i++)
      #pragma unroll
      for (int j = 0; j < 4; j++)
        acc[i][j] = (f32x4){0.f,0.f,0.f,0.f};

    const unsigned short* Arow = Amat + (size_t)mbase*CC + lofs;
    const unsigned short* Brow = Bmat + (size_t)nbase*CC + lofs;
    for (int ks = 0; ks < CC; ks += 32) {
      bf16x8 af[2], bfr[4];
      #pragma unroll
      for (int mt = 0; mt < 2; mt++)
        af[mt] = *(const bf16x8*)(Arow + mt*16*CC + ks*16);
      #pragma unroll
      for (int nt = 0; nt < 4; nt++)
        bfr[nt] = *(const bf16x8*)(Brow + nt*16*CC + ks*16);
      #pragma unroll
      for (int mt = 0; mt < 2; mt++)
        #pragma unroll
        for (int nt = 0; nt < 4; nt++)
          acc[mt][nt] = MFMA16(af[mt], bfr[nt], acc[mt][nt]);
    }

    const float* bias = (which==0) ? bq : bk;
    const float scl = (which==0) ? 0.125f*1.44269504089f : 1.0f;
    unsigned short* Outp = ws + (which==0 ? OFF_Q : OFF_K) + (size_t)b*HH*S*DD;
    #pragma unroll
    for (int mt = 0; mt < 2; mt++){
      const int o = mbase + mt*16 + lg*4;
      const float4 bb = *(const float4*)(bias + o);
      const int hd = o >> 6, db = KI(o & 63);
      #pragma unroll
      for (int nt = 0; nt < 4; nt++){
        const int p = nbase + nt*16 + lq;
        f32x4 v = acc[mt][nt];
        *(ushort4*)(Outp + ((size_t)hd*S + p)*DD + db) =
          pk4f((v[0]+bb.x)*scl, (v[1]+bb.y)*scl, (v[2]+bb.z)*scl, (v[3]+bb.w)*scl);
      }
    }
  } else {
    const int r0 = bid - 512;
    const int b = r0 >> 7;
    const int tile = r0 & 127;
    const int mtile = tile >> 2;
    const int ntile = tile & 3;
    const int mbase = mtile*128 + (wave>>1)*64;
    const int nbase = ntile*64 + (wave&1)*32;
    const unsigned short* Amat = ws + OFF_NX + (size_t)b*S*CC;
    const unsigned short* Bmat = ws + OFF_WV;

    f32x4 acc[4][2];
    #pragma unroll
    for (int i = 0; i < 4; i++)
      #pragma unroll
      for (int j = 0; j < 2; j++)
        acc[i][j] = (f32x4){0.f,0.f,0.f,0.f};

    const unsigned short* Arow = Amat + (size_t)mbase*CC + lofs;
    const unsigned short* Brow = Bmat + (size_t)nbase*CC + lofs;
    for (int ks = 0; ks < CC; ks += 32) {
      bf16x8 af[4], bfr[2];
      #pragma unroll
      for (int mt = 0; mt < 4; mt++)
        af[mt] = *(const bf16x8*)(Arow + mt*16*CC + ks*16);
      #pragma unroll
      for (int nt = 0; nt < 2; nt++)
        bfr[nt] = *(const bf16x8*)(Brow + nt*16*CC + ks*16);
      #pragma unroll
      for (int mt = 0; mt < 4; mt++)
        #pragma unroll
        for (int nt = 0; nt < 2; nt++)
          acc[mt][nt] = MFMA16(af[mt], bfr[nt], acc[mt][nt]);
    }

    unsigned short* Outp = ws + OFF_V + (size_t)b*CC*S;
    #pragma unroll
    for (int nt = 0; nt < 2; nt++){
      const int o = nbase + nt*16 + lq;
      const float bb = bv[o];
      #pragma unroll
      for (int mt = 0; mt < 4; mt++){
        const int p = mbase + mt*16 + lg*4;
        f32x4 v = acc[mt][nt];
        *(ushort4*)(Outp + (size_t)o*S + KI(p)) = pk4f(v[0]+bb, v[1]+bb, v[2]+bb, v[3]+bb);
      }
    }
  }
}

// ---------------- flash attention v9: 3-way split-t + fused last-arriver outproj ----------------
// grid 768: bid = ((ch*32 + qblk)*8) + bh. Per (b,qblk): 12 producer blocks (4h x 3ch).
// The 12th arriver (unsigned mod-12 on an atomic counter -- works from any counter base,
// so no zeroing required) merges the 3 chunks and runs the 128q x 256o output GEMM +
// bias + residual. Counter in ws slack (memset 0 each launch) or the qkv-dead WQ region.
__global__ __launch_bounds__(256, 3) void attn_k(unsigned short* __restrict__ ws,
    const float* __restrict__ bo, const float* __restrict__ x, float* __restrict__ out,
    unsigned int* __restrict__ ctr)
{
  __shared__ __align__(1024) char lds[32768];   // K: 0/8192, V: 16384/24576; tail: merged A-tile
  __shared__ float wtab[128][4][3];
  __shared__ int winflag;
  const int tid = threadIdx.x;
  const int lane = tid & 63, wave = tid >> 6;
  const int lq = lane & 15, lg = lane >> 4;
  const int rsw = (lq & 7) << 4;
  const int bid = blockIdx.x;
  const int bh = bid & 7;
  const int rest = bid >> 3;
  const int qblk = rest & 31;
  const int ch = rest >> 5;                 // 0..2
  const int tBeg = ch*1344 + (ch ? 64 : 0);
  const int tEnd = tBeg + 1344 + (ch ? 0 : 64);
  const unsigned short* Qp = ws + OFF_Q + (size_t)bh*S*DD;
  const unsigned short* Kp = ws + OFF_K + (size_t)bh*S*DD;
  const int b = bh >> 2, h = bh & 3;
  const unsigned short* Vp = ws + OFF_V + ((size_t)b*CC + h*DD)*S;
  const int qbw = qblk*128 + wave*32;

  bf16x8 qf[2][2];
  #pragma unroll
  for (int f = 0; f < 2; f++)
    #pragma unroll
    for (int hh = 0; hh < 2; hh++)
      qf[f][hh] = *(const bf16x8*)(Qp + (size_t)(qbw + f*16 + lq)*DD + hh*32 + lg*8);

  bf16x8 ones;
  #pragma unroll
  for (int i = 0; i < 8; i++) ones[i] = (__bf16)1.0f;

  const int csel = ((lane & 7) ^ ((lane >> 3) & 7)) * 8;
  const int srow = wave*16 + (lane >> 3);
  const int kofs0 = lq*128 + ((lg*16) ^ rsw);
  const int kofs1 = kofs0 ^ 64;

  f32x4 acc[4][2];
  #pragma unroll
  for (int i = 0; i < 4; i++)
    #pragma unroll
    for (int f = 0; f < 2; f++)
      acc[i][f] = (f32x4){0.f,0.f,0.f,0.f};
  f32x4 accL[2] = {(f32x4){0.f,0.f,0.f,0.f}, (f32x4){0.f,0.f,0.f,0.f}};
  float mr[2] = {-1e30f, -1e30f};

  #pragma unroll
  for (int j = 0; j < 2; j++){
    const int row = srow + j*8;
    GLOAD_LDS16(Kp + (size_t)(tBeg + row)*DD + csel, lds + wave*2048 + j*1024);
    GLOAD_LDS16(Vp + (size_t)row*S + tBeg + csel,    lds + 16384 + wave*2048 + j*1024);
  }
  __syncthreads();

  int cur = 0;
  for (int t0 = tBeg; t0 < tEnd; t0 += 64){
    const char* kb = lds + cur*8192;
    const char* vb = lds + 16384 + cur*8192;
    if (t0 + 64 < tEnd){
      char* kn = lds + (cur^1)*8192;
      char* vn = lds + 16384 + (cur^1)*8192;
      #pragma unroll
      for (int j = 0; j < 2; j++){
        const int row = srow + j*8;
        GLOAD_LDS16(Kp + (size_t)(t0 + 64 + row)*DD + csel, kn + wave*2048 + j*1024);
        GLOAD_LDS16(Vp + (size_t)row*S + (t0 + 64) + csel,  vn + wave*2048 + j*1024);
      }
    }
    bf16x8 kf[4][2];
    #pragma unroll
    for (int mt = 0; mt < 4; mt++){
      kf[mt][0] = *(const bf16x8*)(kb + mt*2048 + kofs0);
      kf[mt][1] = *(const bf16x8*)(kb + mt*2048 + kofs1);
    }
    f32x4 st[2][4];
    #pragma unroll
    for (int f = 0; f < 2; f++)
      #pragma unroll
      for (int mt = 0; mt < 4; mt++){
        f32x4 z = (f32x4){0.f,0.f,0.f,0.f};
        z = MFMA16(kf[mt][0], qf[f][0], z);
        z = MFMA16(kf[mt][1], qf[f][1], z);
        st[f][mt] = z;
      }
    bf16x8 vf[4][2];
    #pragma unroll
    for (int dt = 0; dt < 4; dt++){
      vf[dt][0] = *(const bf16x8*)(vb + dt*2048 + kofs0);
      vf[dt][1] = *(const bf16x8*)(vb + dt*2048 + kofs1);
    }
    // per-lane max via v_max3 (cross-lane reduce only inside the rare rescale branch)
    float tmv[2];
    #pragma unroll
    for (int f = 0; f < 2; f++){
      float a0 = max3f(st[f][0][0], st[f][0][1], st[f][0][2]);
      float a1 = max3f(st[f][0][3], st[f][1][0], st[f][1][1]);
      float a2 = max3f(st[f][1][2], st[f][1][3], st[f][2][0]);
      float a3 = max3f(st[f][2][1], st[f][2][2], st[f][2][3]);
      float a4 = max3f(st[f][3][0], st[f][3][1], st[f][3][2]);
      tmv[f] = fmaxf(max3f(a0, a1, st[f][3][3]), fmaxf(a2, max3f(a3, a4, -1e30f)));
    }
    if (!__all((tmv[0] <= mr[0] + 8.f) && (tmv[1] <= mr[1] + 8.f))){
      #pragma unroll
      for (int f = 0; f < 2; f++){
        float tx = fmaxf(tmv[f], __shfl_xor(tmv[f], 16));
        tx = fmaxf(tx, __shfl_xor(tx, 32));
        const float mnew = fmaxf(mr[f], tx);
        const float c = __builtin_amdgcn_exp2f(mr[f] - mnew);
        #pragma unroll
        for (int dt = 0; dt < 4; dt++)
          #pragma unroll
          for (int r = 0; r < 4; r++)
            acc[dt][f][r] *= c;
        #pragma unroll
        for (int r = 0; r < 4; r++) accL[f][r] *= c;
        mr[f] = mnew;
      }
    }
    union PU { bf16x8 v; unsigned u[4]; } p0[2], p1[2];
    #pragma unroll
    for (int f = 0; f < 2; f++){
      #pragma unroll
      for (int mt = 0; mt < 4; mt++){
        float e0 = __builtin_amdgcn_exp2f(st[f][mt][0] - mr[f]);
        float e1 = __builtin_amdgcn_exp2f(st[f][mt][1] - mr[f]);
        float e2 = __builtin_amdgcn_exp2f(st[f][mt][2] - mr[f]);
        float e3 = __builtin_amdgcn_exp2f(st[f][mt][3] - mr[f]);
        if (mt < 2){ p0[f].u[mt*2] = cvtpk(e0, e1); p0[f].u[mt*2+1] = cvtpk(e2, e3); }
        else       { p1[f].u[(mt-2)*2] = cvtpk(e0, e1); p1[f].u[(mt-2)*2+1] = cvtpk(e2, e3); }
      }
    }
    // PV + l-sum (ones-A MFMA)
    #pragma unroll
    for (int dt = 0; dt < 4; dt++)
      #pragma unroll
      for (int f = 0; f < 2; f++){
        f32x4 a = acc[dt][f];
        a = MFMA16(vf[dt][0], p0[f].v, a);
        a = MFMA16(vf[dt][1], p1[f].v, a);
        acc[dt][f] = a;
      }
    #pragma unroll
    for (int f = 0; f < 2; f++){
      accL[f] = MFMA16(ones, p0[f].v, accL[f]);
      accL[f] = MFMA16(ones, p1[f].v, accL[f]);
    }
    __syncthreads();
    cur ^= 1;
  }

  // epilogue: unnormalized partials (PACC bf16) + m/l
  unsigned short* PA = pacc_base(ws, ch) + (size_t)bh*S*DD;
  float* ML = (float*)(ws + OFF_Q) + ((size_t)ch*8 + bh)*S*2;
  #pragma unroll
  for (int f = 0; f < 2; f++){
    const int q = qbw + f*16 + lq;
    #pragma unroll
    for (int dt = 0; dt < 4; dt++)
      *(ushort4*)(PA + (size_t)q*DD + dt*16 + lg*4) = pk4(acc[dt][f]);
    if (lg == 0){
      ML[(size_t)q*2]   = mr[f];
      ML[(size_t)q*2+1] = accL[f][0];
    }
  }

  // ---- last-arriver fused output projection ----
  __threadfence();
  __syncthreads();
  if (tid == 0){
    unsigned old = atomicAdd(&ctr[b*32 + qblk], 1u);
    winflag = ((old % 12u) == 11u);
  }
  __syncthreads();
  if (!winflag) return;
  __threadfence();   // acquire: other XCDs' PACC/ML now visible

  // merge weights for this (b, 128q)
  const float* MLb = (const float*)(ws + OFF_Q);
  #pragma unroll
  for (int it = 0; it < 2; it++){
    const int idx = it*256 + tid;           // 512 = 128q x 4h
    const int ql = idx >> 2, hh = idx & 3;
    const int q = qblk*128 + ql;
    float m0, m1, m2, l0, l1, l2;
    {
      const float* p0p = MLb + (((size_t)0*8 + b*4 + hh)*S + q)*2;
      const float* p1p = MLb + (((size_t)1*8 + b*4 + hh)*S + q)*2;
      const float* p2p = MLb + (((size_t)2*8 + b*4 + hh)*S + q)*2;
      m0 = p0p[0]; l0 = p0p[1];
      m1 = p1p[0]; l1 = p1p[1];
      m2 = p2p[0]; l2 = p2p[1];
    }
    const float M = max3f(m0, m1, m2);
    const float w0 = __builtin_amdgcn_exp2f(m0 - M);
    const float w1 = __builtin_amdgcn_exp2f(m1 - M);
    const float w2 = __builtin_amdgcn_exp2f(m2 - M);
    const float inv = 1.0f / (w0*l0 + w1*l1 + w2*l2);
    wtab[ql][hh][0] = w0*inv; wtab[ql][hh][1] = w1*inv; wtab[ql][hh][2] = w2*inv;
  }
  __syncthreads();

  const int lofs = lq*32 + lg*8;
  unsigned short* ldsA = (unsigned short*)lds;
  #pragma unroll
  for (int qh = 0; qh < 2; qh++){
    const int qg = qblk*128 + qh*64;
    // merge 64q x 256c into blocked LDS A-tile
    #pragma unroll
    for (int it = 0; it < 16; it++){
      const int w = it*256 + tid;
      const int ql = w >> 6, cq = w & 63;
      const int hh = cq >> 4, d = (cq & 15)*4;
      const size_t po = ((size_t)(b*4 + hh)*S + qg + ql)*DD + d;
      const ushort4 a0 = *(const ushort4*)(ws + OFF_NY + po);
      const ushort4 a1 = *(const ushort4*)(ws + OFF_NX + po);
      const ushort4 a2 = *(const ushort4*)(ws + OFF_AO + po);
      const float w0 = wtab[qh*64 + ql][hh][0];
      const float w1 = wtab[qh*64 + ql][hh][1];
      const float w2 = wtab[qh*64 + ql][hh][2];
      *(ushort4*)(ldsA + BL256(ql, cq*4)) = pk4f(
        bf2f(a0.x)*w0 + bf2f(a1.x)*w1 + bf2f(a2.x)*w2,
        bf2f(a0.y)*w0 + bf2f(a1.y)*w1 + bf2f(a2.y)*w2,
        bf2f(a0.z)*w0 + bf2f(a1.z)*w1 + bf2f(a2.z)*w2,
        bf2f(a0.w)*w0 + bf2f(a1.w)*w1 + bf2f(a2.w)*w2);
    }
    __syncthreads();
    // GEMM 64q x 256o: wave = 32q x 128o
    const int mb = (wave >> 1)*32;
    const int nb = (wave & 1)*128;
    f32x4 acc2[2][8];
    #pragma unroll
    for (int i = 0; i < 2; i++)
      #pragma unroll
      for (int j = 0; j < 8; j++)
        acc2[i][j] = (f32x4){0.f,0.f,0.f,0.f};
    const unsigned short* Arow = ldsA + (size_t)mb*CC + lofs;
    const unsigned short* Brow = ws + OFF_WO + (size_t)nb*CC + lofs;
    for (int ks = 0; ks < CC; ks += 32){
      bf16x8 af[2], bfr[8];
      #pragma unroll
      for (int mt = 0; mt < 2; mt++)
        af[mt] = *(const bf16x8*)(Arow + mt*16*CC + ks*16);
      #pragma unroll
      for (int nt = 0; nt < 8; nt++)
        bfr[nt] = *(const bf16x8*)(Brow + nt*16*CC + ks*16);
      #pragma unroll
      for (int mt = 0; mt < 2; mt++)
        #pragma unroll
        for (int nt = 0; nt < 8; nt++)
          acc2[mt][nt] = MFMA16(af[mt], bfr[nt], acc2[mt][nt]);
    }
    #pragma unroll
    for (int nt = 0; nt < 8; nt++){
      const int o = nb + nt*16 + lq;
      const float bb = bo[o];
      #pragma unroll
      for (int mt = 0; mt < 2; mt++){
        const int p = qg + mb + mt*16 + lg*4;
        const size_t idx = ((size_t)b*CC + o)*S + p;
        const float4 xr = *(const float4*)(x + idx);
        f32x4 v = acc2[mt][nt];
        float4 r; r.x = v[0]+bb+xr.x; r.y = v[1]+bb+xr.y; r.z = v[2]+bb+xr.z; r.w = v[3]+bb+xr.w;
        *(float4*)(out + idx) = r;
      }
    }
    __syncthreads();   // ldsA reused next pass
  }
}

extern "C" void kernel_launch(void* const* d_in, const int* in_sizes, int n_in,
                              void* d_out, int out_size, void* d_ws, size_t ws_size,
                              hipStream_t stream) {
  const float* x  = (const float*)d_in[0];
  const float* y  = (const float*)d_in[1];
  const float* g1 = (const float*)d_in[2];
  const float* b1 = (const float*)d_in[3];
  const float* g2 = (const float*)d_in[4];
  const float* b2 = (const float*)d_in[5];
  const float* wq = (const float*)d_in[6];
  const float* bq = (const float*)d_in[7];
  const float* wk = (const float*)d_in[8];
  const float* bk = (const float*)d_in[9];
  const float* wv = (const float*)d_in[10];
  const float* bv = (const float*)d_in[11];
  const float* wo = (const float*)d_in[12];
  const float* bo = (const float*)d_in[13];
  float* out = (float*)d_out;
  unsigned short* ws16 = (unsigned short*)d_ws;

  // Counter placement: ws slack if available (zeroed each launch -> base 0),
  // else the qkv-dead WQ region (deterministic garbage base; mod-12 handles it).
  unsigned int* ctr;
  if (ws_size >= WS_NEED_BYTES + 256){
    ctr = (unsigned int*)((char*)d_ws + WS_NEED_BYTES);
    hipMemsetAsync(ctr, 0, 256, stream);
  } else {
    ctr = (unsigned int*)(ws16 + OFF_WQ);
  }

  prep_k  <<<384, 256, 0, stream>>>(x, y, g1, b1, g2, b2, wq, wk, wv, wo, ws16);
  qkv_gemm<<<768, 256, 0, stream>>>(ws16, bq, bk, bv);
  attn_k  <<<768, 256, 0, stream>>>(ws16, bo, x, out, ctr);
}

// Round 11
// 107.778 us; speedup vs baseline: 1.8089x; 1.8089x over previous
//
#include <hip/hip_runtime.h>

typedef __bf16 bf16_t;
typedef bf16_t bf16x8 __attribute__((ext_vector_type(8)));
typedef float f32x4 __attribute__((ext_vector_type(4)));

#define MFMA16(a,b,c) __builtin_amdgcn_mfma_f32_16x16x32_bf16((a),(b),(c),0,0,0)

#define GLOAD_LDS16(gsrc, ldst) \
  __builtin_amdgcn_global_load_lds((const __attribute__((address_space(1))) unsigned int*)(gsrc), \
                                   (__attribute__((address_space(3))) unsigned int*)(ldst), 16, 0, 0)

__device__ __forceinline__ unsigned short f2bf(float f){
  unsigned int u = __builtin_bit_cast(unsigned int, f);
  u = (u + 0x7FFFu + ((u >> 16) & 1u)) >> 16;
  return (unsigned short)u;
}
__device__ __forceinline__ float bf2f(unsigned short u){
  return __builtin_bit_cast(float, (unsigned int)u << 16);
}
__device__ __forceinline__ ushort4 pk4(f32x4 v){
  union { __bf16 b[4]; ushort4 u; } r;
  r.b[0]=(__bf16)v[0]; r.b[1]=(__bf16)v[1]; r.b[2]=(__bf16)v[2]; r.b[3]=(__bf16)v[3];
  return r.u;
}

// KI: k-interleave within 64-elem segment (for Q/K/V consumed by attention).
__device__ __forceinline__ int KI(int d){   // d 4-aligned
  int gi = (d >> 2) & 15;
  int pos = (gi & 8) | ((gi & 3) << 1) | ((gi >> 2) & 1);
  return (d & ~63) | (pos << 2);
}

// Blocked fragment layout for GEMM operands [R][256]:
// wave fragment load at (rowbase*256 + ks*16 + lq*32 + lg*8) is contiguous 1KB.
__device__ __forceinline__ int BL256(int r, int c){
  return ((r >> 4) << 12) + (((c >> 5)) << 9) + ((r & 15) << 5)
       + (((c & 15) >> 2) << 3) + (((c >> 4) & 1) << 2) + (c & 3);
}

constexpr int BN = 2;
constexpr int CC = 256;
constexpr int S  = 4096;
constexpr int HH = 4;
constexpr int DD = 64;

constexpr size_t OFF_WQ = 0;
constexpr size_t OFF_WK = 65536;
constexpr size_t OFF_WV = 131072;
constexpr size_t OFF_WO = 196608;
constexpr size_t OFF_NY = 262144;                      // blocked [p][c]
constexpr size_t OFF_NX = OFF_NY + (size_t)BN*S*CC;    // blocked [p][c]
constexpr size_t OFF_Q  = OFF_NX + (size_t)BN*S*CC;    // [b][h][p][d~KI] (pre-scaled 0.125*log2e)
constexpr size_t OFF_K  = OFF_Q  + (size_t)BN*S*CC;    // [b][h][p][d~KI]
constexpr size_t OFF_V  = OFF_K  + (size_t)BN*S*CC;    // [b][c][p~KI]
constexpr size_t OFF_AO = OFF_V  + (size_t)BN*S*CC;    // (dead after qkv: reused as PACC ch2)
// Attention partials (3 t-chunks): ch0->NY, ch1->NX, ch2->AO (dead after qkv_gemm).
// ML [3][8][4096][2] f32 overlays OFF_Q (clobbers Q[bh0..1.5]). SAFE: attn grid (768)
// is fully co-resident (3 blocks/CU via __launch_bounds__(256,3)); every block reads Q
// in its prologue long before any epilogue ML write. qkv rewrites Q each call.
__device__ __forceinline__ unsigned short* pacc_base(unsigned short* ws, int ch){
  return ws + (ch == 0 ? OFF_NY : (ch == 1 ? OFF_NX : OFF_AO));
}

// ---------------- fused weight-convert + GroupNorm ----------------
__global__ __launch_bounds__(256) void prep_k(const float* __restrict__ x, const float* __restrict__ y,
    const float* __restrict__ g1, const float* __restrict__ b1,
    const float* __restrict__ g2, const float* __restrict__ b2,
    const float* __restrict__ wq, const float* __restrict__ wk,
    const float* __restrict__ wv, const float* __restrict__ wo,
    unsigned short* __restrict__ ws)
{
  __shared__ float red[8];
  __shared__ float mv[2];
  const int tid = threadIdx.x;
  const int bid = blockIdx.x;

  if (bid >= 128){
    const int idx = (bid - 128)*256 + tid;
    const int m = idx >> 14;
    const int off = (idx & 16383) << 2;
    const float* src = (m==0) ? wq : (m==1) ? wk : (m==2) ? wv : wo;
    float4 v = *(const float4*)(src + off);
    ushort4 r; r.x=f2bf(v.x); r.y=f2bf(v.y); r.z=f2bf(v.z); r.w=f2bf(v.w);
    const int o = off >> 8, c = off & 255;
    *(ushort4*)(ws + (size_t)m*65536 + BL256(o, c)) = r;
    return;
  }

  const int tsel = bid >> 6;
  const int rem  = bid & 63;
  const int b = rem >> 5, g = rem & 31;
  const float* in = (tsel ? y : x) + ((size_t)b*CC + g*8)*S;
  unsigned short* outp = ws + (tsel ? OFF_NY : OFF_NX) + (size_t)b*S*CC;
  const int j = g & 3;
  const int gk = (g >> 2) * 512;
  const int posA = (j & 1)*16 + (j >> 1)*4;
  const int posB = posA + 8;
  const float* gamma = (tsel ? g2 : g1) + g*8;
  const float* beta  = (tsel ? b2 : b1) + g*8;

  float s = 0.f, ss = 0.f;
  #pragma unroll
  for (int ci = 0; ci < 8; ci++){
    const float4* row = (const float4*)(in + (size_t)ci*S);
    #pragma unroll
    for (int i = 0; i < 4; i++){
      float4 v = row[tid + i*256];
      s  += v.x + v.y + v.z + v.w;
      ss += v.x*v.x + v.y*v.y + v.z*v.z + v.w*v.w;
    }
  }
  #pragma unroll
  for (int off = 1; off < 64; off <<= 1){
    s  += __shfl_xor(s,  off);
    ss += __shfl_xor(ss, off);
  }
  const int wave = tid >> 6, lane = tid & 63;
  if (lane == 0){ red[wave] = s; red[4+wave] = ss; }
  __syncthreads();
  if (tid == 0){
    float S1 = red[0]+red[1]+red[2]+red[3];
    float S2 = red[4]+red[5]+red[6]+red[7];
    const float invn = 1.0f/32768.0f;
    float mean = S1*invn;
    float var  = S2*invn - mean*mean;
    mv[0] = mean; mv[1] = rsqrtf(var + 1e-6f);
  }
  __syncthreads();
  const float mean = mv[0], rstd = mv[1];
  float sc[8], sh[8];
  #pragma unroll
  for (int ci = 0; ci < 8; ci++){ sc[ci] = rstd*gamma[ci]; sh[ci] = beta[ci] - mean*sc[ci]; }
  for (int i = 0; i < 16; i++){
    const int p = tid + i*256;
    const int base = ((p >> 4) << 12) + gk + ((p & 15) << 5);
    ushort4 a0, a1;
    a0.x = f2bf(in[0*S+p]*sc[0]+sh[0]);
    a0.y = f2bf(in[1*S+p]*sc[1]+sh[1]);
    a0.z = f2bf(in[2*S+p]*sc[2]+sh[2]);
    a0.w = f2bf(in[3*S+p]*sc[3]+sh[3]);
    a1.x = f2bf(in[4*S+p]*sc[4]+sh[4]);
    a1.y = f2bf(in[5*S+p]*sc[5]+sh[5]);
    a1.z = f2bf(in[6*S+p]*sc[6]+sh[6]);
    a1.w = f2bf(in[7*S+p]*sc[7]+sh[7]);
    *(ushort4*)(outp + base + posA) = a0;
    *(ushort4*)(outp + base + posB) = a1;
  }
}

// ---------------- Q/K/V projection GEMMs, 768 blocks (3/CU) ----------------
__global__ __launch_bounds__(256, 3) void qkv_gemm(unsigned short* __restrict__ ws,
    const float* __restrict__ bq, const float* __restrict__ bk, const float* __restrict__ bv)
{
  const int tid = threadIdx.x;
  const int lane = tid & 63, wave = tid >> 6;
  const int lq = lane & 15, lg = lane >> 4;
  const int lofs = lq*32 + lg*8;
  const int bid = blockIdx.x;

  if (bid < 512){
    const int inst2 = bid >> 7;             // 0..3
    const int which = inst2 >> 1;           // 0=Q,1=K
    const int b = inst2 & 1;
    const int tile = bid & 127;
    const int mtile = tile & 3;
    const int ntile = tile >> 2;
    const int mbase = mtile*64 + (wave>>1)*32;
    const int nbase = ntile*128 + (wave&1)*64;
    const unsigned short* Amat = ws + (which==0 ? OFF_WQ : OFF_WK);
    const unsigned short* Bmat = ws + (which==0 ? OFF_NY : OFF_NX) + (size_t)b*S*CC;

    f32x4 acc[2][4];
    #pragma unroll
    for (int i = 0; i < 2; i++)
      #pragma unroll
      for (int j = 0; j < 4; j++)
        acc[i][j] = (f32x4){0.f,0.f,0.f,0.f};

    const unsigned short* Arow = Amat + (size_t)mbase*CC + lofs;
    const unsigned short* Brow = Bmat + (size_t)nbase*CC + lofs;
    for (int ks = 0; ks < CC; ks += 32) {
      bf16x8 af[2], bfr[4];
      #pragma unroll
      for (int mt = 0; mt < 2; mt++)
        af[mt] = *(const bf16x8*)(Arow + mt*16*CC + ks*16);
      #pragma unroll
      for (int nt = 0; nt < 4; nt++)
        bfr[nt] = *(const bf16x8*)(Brow + nt*16*CC + ks*16);
      #pragma unroll
      for (int mt = 0; mt < 2; mt++)
        #pragma unroll
        for (int nt = 0; nt < 4; nt++)
          acc[mt][nt] = MFMA16(af[mt], bfr[nt], acc[mt][nt]);
    }

    const float* bias = (which==0) ? bq : bk;
    const float scl = (which==0) ? 0.125f*1.44269504089f : 1.0f;
    unsigned short* Outp = ws + (which==0 ? OFF_Q : OFF_K) + (size_t)b*HH*S*DD;
    #pragma unroll
    for (int mt = 0; mt < 2; mt++){
      const int o = mbase + mt*16 + lg*4;
      const float4 bb = *(const float4*)(bias + o);
      const int hd = o >> 6, db = KI(o & 63);
      #pragma unroll
      for (int nt = 0; nt < 4; nt++){
        const int p = nbase + nt*16 + lq;
        f32x4 v = acc[mt][nt];
        ushort4 r;
        r.x = f2bf((v[0]+bb.x)*scl); r.y = f2bf((v[1]+bb.y)*scl);
        r.z = f2bf((v[2]+bb.z)*scl); r.w = f2bf((v[3]+bb.w)*scl);
        *(ushort4*)(Outp + ((size_t)hd*S + p)*DD + db) = r;
      }
    }
  } else {
    const int r0 = bid - 512;
    const int b = r0 >> 7;
    const int tile = r0 & 127;
    const int mtile = tile >> 2;
    const int ntile = tile & 3;
    const int mbase = mtile*128 + (wave>>1)*64;
    const int nbase = ntile*64 + (wave&1)*32;
    const unsigned short* Amat = ws + OFF_NX + (size_t)b*S*CC;
    const unsigned short* Bmat = ws + OFF_WV;

    f32x4 acc[4][2];
    #pragma unroll
    for (int i = 0; i < 4; i++)
      #pragma unroll
      for (int j = 0; j < 2; j++)
        acc[i][j] = (f32x4){0.f,0.f,0.f,0.f};

    const unsigned short* Arow = Amat + (size_t)mbase*CC + lofs;
    const unsigned short* Brow = Bmat + (size_t)nbase*CC + lofs;
    for (int ks = 0; ks < CC; ks += 32) {
      bf16x8 af[4], bfr[2];
      #pragma unroll
      for (int mt = 0; mt < 4; mt++)
        af[mt] = *(const bf16x8*)(Arow + mt*16*CC + ks*16);
      #pragma unroll
      for (int nt = 0; nt < 2; nt++)
        bfr[nt] = *(const bf16x8*)(Brow + nt*16*CC + ks*16);
      #pragma unroll
      for (int mt = 0; mt < 4; mt++)
        #pragma unroll
        for (int nt = 0; nt < 2; nt++)
          acc[mt][nt] = MFMA16(af[mt], bfr[nt], acc[mt][nt]);
    }

    unsigned short* Outp = ws + OFF_V + (size_t)b*CC*S;
    #pragma unroll
    for (int nt = 0; nt < 2; nt++){
      const int o = nbase + nt*16 + lq;
      const float bb = bv[o];
      #pragma unroll
      for (int mt = 0; mt < 4; mt++){
        const int p = mbase + mt*16 + lg*4;
        f32x4 v = acc[mt][nt];
        ushort4 r;
        r.x = f2bf(v[0]+bb); r.y = f2bf(v[1]+bb);
        r.z = f2bf(v[2]+bb); r.w = f2bf(v[3]+bb);
        *(ushort4*)(Outp + (size_t)o*S + KI(p)) = r;
      }
    }
  }
}

// ---------------- flash attention: 3-way split-t, 3 blocks/CU, MFMA l-sum ----------------
// grid 768: bid = ((ch*32 + qblk)*8) + bh. 4 waves x 32 q = 128 q per block.
// t-chunks: ch0=[0,1408) 22 steps, ch1=[1408,2752) 21, ch2=[2752,4096) 21.
// K/V LDS [64][64] double-buffered (0-conflict layout), global_load_lds staging.
// l accumulated via MFMA with all-ones A-operand.
__global__ __launch_bounds__(256, 3) void attn_k(unsigned short* __restrict__ ws)
{
  __shared__ __align__(1024) char lds[32768];   // K: 0/8192, V: 16384/24576
  const int tid = threadIdx.x;
  const int lane = tid & 63, wave = tid >> 6;
  const int lq = lane & 15, lg = lane >> 4;
  const int rsw = (lq & 7) << 4;
  const int bid = blockIdx.x;
  const int bh = bid & 7;
  const int rest = bid >> 3;                // 0..95
  const int qblk = rest & 31;
  const int ch = rest >> 5;                 // 0..2
  const int tBeg = ch*1344 + (ch ? 64 : 0);
  const int tEnd = tBeg + 1344 + (ch ? 0 : 64);
  const unsigned short* Qp = ws + OFF_Q + (size_t)bh*S*DD;
  const unsigned short* Kp = ws + OFF_K + (size_t)bh*S*DD;
  const int b = bh >> 2, h = bh & 3;
  const unsigned short* Vp = ws + OFF_V + ((size_t)b*CC + h*DD)*S;
  const int qbw = qblk*128 + wave*32;

  bf16x8 qf[2][2];
  #pragma unroll
  for (int f = 0; f < 2; f++)
    #pragma unroll
    for (int hh = 0; hh < 2; hh++)
      qf[f][hh] = *(const bf16x8*)(Qp + (size_t)(qbw + f*16 + lq)*DD + hh*32 + lg*8);

  bf16x8 ones;
  #pragma unroll
  for (int i = 0; i < 8; i++) ones[i] = (__bf16)1.0f;

  const int csel = ((lane & 7) ^ ((lane >> 3) & 7)) * 8;
  const int srow = wave*16 + (lane >> 3);
  const int kofs0 = lq*128 + ((lg*16) ^ rsw);
  const int kofs1 = kofs0 ^ 64;

  f32x4 acc[4][2];
  #pragma unroll
  for (int i = 0; i < 4; i++)
    #pragma unroll
    for (int f = 0; f < 2; f++)
      acc[i][f] = (f32x4){0.f,0.f,0.f,0.f};
  f32x4 accL[2] = {(f32x4){0.f,0.f,0.f,0.f}, (f32x4){0.f,0.f,0.f,0.f}};
  float mr[2] = {-1e30f, -1e30f};

  #pragma unroll
  for (int j = 0; j < 2; j++){
    const int row = srow + j*8;
    GLOAD_LDS16(Kp + (size_t)(tBeg + row)*DD + csel, lds + wave*2048 + j*1024);
    GLOAD_LDS16(Vp + (size_t)row*S + tBeg + csel,    lds + 16384 + wave*2048 + j*1024);
  }
  __syncthreads();

  int cur = 0;
  for (int t0 = tBeg; t0 < tEnd; t0 += 64){
    const char* kb = lds + cur*8192;
    const char* vb = lds + 16384 + cur*8192;
    if (t0 + 64 < tEnd){
      char* kn = lds + (cur^1)*8192;
      char* vn = lds + 16384 + (cur^1)*8192;
      #pragma unroll
      for (int j = 0; j < 2; j++){
        const int row = srow + j*8;
        GLOAD_LDS16(Kp + (size_t)(t0 + 64 + row)*DD + csel, kn + wave*2048 + j*1024);
        GLOAD_LDS16(Vp + (size_t)row*S + (t0 + 64) + csel,  vn + wave*2048 + j*1024);
      }
    }
    bf16x8 kf[4][2];
    #pragma unroll
    for (int mt = 0; mt < 4; mt++){
      kf[mt][0] = *(const bf16x8*)(kb + mt*2048 + kofs0);
      kf[mt][1] = *(const bf16x8*)(kb + mt*2048 + kofs1);
    }
    f32x4 st[2][4];
    #pragma unroll
    for (int f = 0; f < 2; f++)
      #pragma unroll
      for (int mt = 0; mt < 4; mt++){
        f32x4 z = (f32x4){0.f,0.f,0.f,0.f};
        z = MFMA16(kf[mt][0], qf[f][0], z);
        z = MFMA16(kf[mt][1], qf[f][1], z);
        st[f][mt] = z;
      }
    bf16x8 vf[4][2];
    #pragma unroll
    for (int dt = 0; dt < 4; dt++){
      vf[dt][0] = *(const bf16x8*)(vb + dt*2048 + kofs0);
      vf[dt][1] = *(const bf16x8*)(vb + dt*2048 + kofs1);
    }
    // online softmax (exp2 domain), combined defer-max THR=8
    float tmv[2];
    #pragma unroll
    for (int f = 0; f < 2; f++){
      float tm = fmaxf(
        fmaxf(fmaxf(fmaxf(st[f][0][0], st[f][0][1]), fmaxf(st[f][0][2], st[f][0][3])),
              fmaxf(fmaxf(st[f][1][0], st[f][1][1]), fmaxf(st[f][1][2], st[f][1][3]))),
        fmaxf(fmaxf(fmaxf(st[f][2][0], st[f][2][1]), fmaxf(st[f][2][2], st[f][2][3])),
              fmaxf(fmaxf(st[f][3][0], st[f][3][1]), fmaxf(st[f][3][2], st[f][3][3]))));
      tm = fmaxf(tm, __shfl_xor(tm, 16));
      tm = fmaxf(tm, __shfl_xor(tm, 32));
      tmv[f] = tm;
    }
    if (!__all((tmv[0] <= mr[0] + 8.f) && (tmv[1] <= mr[1] + 8.f))){
      #pragma unroll
      for (int f = 0; f < 2; f++){
        const float mnew = fmaxf(mr[f], tmv[f]);
        const float c = __builtin_amdgcn_exp2f(mr[f] - mnew);
        #pragma unroll
        for (int dt = 0; dt < 4; dt++)
          #pragma unroll
          for (int r = 0; r < 4; r++)
            acc[dt][f][r] *= c;
        #pragma unroll
        for (int r = 0; r < 4; r++) accL[f][r] *= c;
        mr[f] = mnew;
      }
    }
    union PU { bf16x8 v; __bf16 e[8]; } p0[2], p1[2];
    #pragma unroll
    for (int f = 0; f < 2; f++){
      #pragma unroll
      for (int mt = 0; mt < 4; mt++)
        #pragma unroll
        for (int r = 0; r < 4; r++){
          float e = __builtin_amdgcn_exp2f(st[f][mt][r] - mr[f]);
          if (mt < 2) p0[f].e[mt*4+r] = (__bf16)e;
          else        p1[f].e[(mt-2)*4+r] = (__bf16)e;
        }
    }
    // PV + l-sum (ones-A MFMA)
    #pragma unroll
    for (int dt = 0; dt < 4; dt++)
      #pragma unroll
      for (int f = 0; f < 2; f++){
        f32x4 a = acc[dt][f];
        a = MFMA16(vf[dt][0], p0[f].v, a);
        a = MFMA16(vf[dt][1], p1[f].v, a);
        acc[dt][f] = a;
      }
    #pragma unroll
    for (int f = 0; f < 2; f++){
      accL[f] = MFMA16(ones, p0[f].v, accL[f]);
      accL[f] = MFMA16(ones, p1[f].v, accL[f]);
    }
    __syncthreads();
    cur ^= 1;
  }

  // epilogue: unnormalized partials (PACC bf16) + m/l
  unsigned short* PA = pacc_base(ws, ch) + (size_t)bh*S*DD;
  float* ML = (float*)(ws + OFF_Q) + ((size_t)ch*8 + bh)*S*2;
  #pragma unroll
  for (int f = 0; f < 2; f++){
    const int q = qbw + f*16 + lq;
    #pragma unroll
    for (int dt = 0; dt < 4; dt++)
      *(ushort4*)(PA + (size_t)q*DD + dt*16 + lg*4) = pk4(acc[dt][f]);
    if (lg == 0){
      ML[(size_t)q*2]   = mr[f];
      ML[(size_t)q*2+1] = accL[f][0];
    }
  }
}

// ---------------- output projection: merge + GEMM + residual, 512 blocks (2/CU) ----------------
// tile 64q x 64o; wave = 32q x 32o.
__global__ __launch_bounds__(256, 2) void outproj_k(unsigned short* __restrict__ ws,
    const float* __restrict__ bo, const float* __restrict__ x, float* __restrict__ out)
{
  __shared__ unsigned short ldsA[16384];    // 64 x 256 blocked, 32KB
  __shared__ float wtab[64][4][3];
  const int tid = threadIdx.x;
  const int lane = tid & 63, wave = tid >> 6;
  const int lq = lane & 15, lg = lane >> 4;
  const int lofs = lq*32 + lg*8;
  const int bid = blockIdx.x;
  const int b = bid >> 8;
  const int r0 = bid & 255;
  const int mtile = r0 >> 2;                // 64 q-tiles of 64
  const int ntile = r0 & 3;                 // 4 o-tiles of 64
  const int qg = mtile*64;

  // phase 1: merge weights per (q,h)
  {
    const int q = tid >> 2, h = tid & 3;
    const float* MLb = (const float*)(ws + OFF_Q);
    float m[3], l[3];
    #pragma unroll
    for (int c = 0; c < 3; c++){
      const float* p = MLb + (((size_t)c*8 + b*4 + h)*S + (qg + q))*2;
      m[c] = p[0]; l[c] = p[1];
    }
    const float M = fmaxf(m[0], fmaxf(m[1], m[2]));
    const float w0 = __builtin_amdgcn_exp2f(m[0] - M);
    const float w1 = __builtin_amdgcn_exp2f(m[1] - M);
    const float w2 = __builtin_amdgcn_exp2f(m[2] - M);
    const float inv = 1.0f / (w0*l[0] + w1*l[1] + w2*l[2]);
    wtab[q][h][0] = w0*inv; wtab[q][h][1] = w1*inv; wtab[q][h][2] = w2*inv;
  }
  __syncthreads();

  // phase 2: merge 64q x 256c into blocked LDS A-tile
  #pragma unroll
  for (int it = 0; it < 16; it++){
    const int w = it*256 + tid;
    const int q = w >> 6, cq = w & 63;
    const int h = cq >> 4, d = (cq & 15)*4;
    const size_t po = ((size_t)(b*4 + h)*S + (qg + q))*DD + d;
    const ushort4 a0 = *(const ushort4*)(ws + OFF_NY + po);
    const ushort4 a1 = *(const ushort4*)(ws + OFF_NX + po);
    const ushort4 a2 = *(const ushort4*)(ws + OFF_AO + po);
    const float w0 = wtab[q][h][0], w1 = wtab[q][h][1], w2 = wtab[q][h][2];
    f32x4 v;
    v[0] = bf2f(a0.x)*w0 + bf2f(a1.x)*w1 + bf2f(a2.x)*w2;
    v[1] = bf2f(a0.y)*w0 + bf2f(a1.y)*w1 + bf2f(a2.y)*w2;
    v[2] = bf2f(a0.z)*w0 + bf2f(a1.z)*w1 + bf2f(a2.z)*w2;
    v[3] = bf2f(a0.w)*w0 + bf2f(a1.w)*w1 + bf2f(a2.w)*w2;
    *(ushort4*)(ldsA + BL256(q, cq*4)) = pk4(v);
  }
  __syncthreads();

  // phase 3: GEMM (A from LDS, B=WO from global) + bias + residual
  const int mbase = (wave>>1)*32;           // local q base
  const int nbase = ntile*64 + (wave&1)*32; // global o base
  f32x4 acc[2][2];
  #pragma unroll
  for (int i = 0; i < 2; i++)
    #pragma unroll
    for (int j = 0; j < 2; j++)
      acc[i][j] = (f32x4){0.f,0.f,0.f,0.f};
  const unsigned short* Arow = ldsA + (size_t)mbase*CC + lofs;
  const unsigned short* Brow = ws + OFF_WO + (size_t)nbase*CC + lofs;
  for (int ks = 0; ks < CC; ks += 32) {
    bf16x8 af[2], bfr[2];
    #pragma unroll
    for (int mt = 0; mt < 2; mt++)
      af[mt] = *(const bf16x8*)(Arow + mt*16*CC + ks*16);
    #pragma unroll
    for (int nt = 0; nt < 2; nt++)
      bfr[nt] = *(const bf16x8*)(Brow + nt*16*CC + ks*16);
    #pragma unroll
    for (int mt = 0; mt < 2; mt++)
      #pragma unroll
      for (int nt = 0; nt < 2; nt++)
        acc[mt][nt] = MFMA16(af[mt], bfr[nt], acc[mt][nt]);
  }
  #pragma unroll
  for (int nt = 0; nt < 2; nt++){
    const int o = nbase + nt*16 + lq;
    const float bb = bo[o];
    #pragma unroll
    for (int mt = 0; mt < 2; mt++){
      const int p = qg + mbase + mt*16 + lg*4;
      const size_t idx = ((size_t)b*CC + o)*S + p;
      const float4 xr = *(const float4*)(x + idx);
      f32x4 v = acc[mt][nt];
      float4 r; r.x = v[0]+bb+xr.x; r.y = v[1]+bb+xr.y; r.z = v[2]+bb+xr.z; r.w = v[3]+bb+xr.w;
      *(float4*)(out + idx) = r;
    }
  }
}

extern "C" void kernel_launch(void* const* d_in, const int* in_sizes, int n_in,
                              void* d_out, int out_size, void* d_ws, size_t ws_size,
                              hipStream_t stream) {
  const float* x  = (const float*)d_in[0];
  const float* y  = (const float*)d_in[1];
  const float* g1 = (const float*)d_in[2];
  const float* b1 = (const float*)d_in[3];
  const float* g2 = (const float*)d_in[4];
  const float* b2 = (const float*)d_in[5];
  const float* wq = (const float*)d_in[6];
  const float* bq = (const float*)d_in[7];
  const float* wk = (const float*)d_in[8];
  const float* bk = (const float*)d_in[9];
  const float* wv = (const float*)d_in[10];
  const float* bv = (const float*)d_in[11];
  const float* wo = (const float*)d_in[12];
  const float* bo = (const float*)d_in[13];
  float* out = (float*)d_out;
  unsigned short* ws16 = (unsigned short*)d_ws;

  prep_k   <<<384, 256, 0, stream>>>(x, y, g1, b1, g2, b2, wq, wk, wv, wo, ws16);
  qkv_gemm <<<768, 256, 0, stream>>>(ws16, bq, bk, bv);
  attn_k   <<<768, 256, 0, stream>>>(ws16);
  outproj_k<<<512, 256, 0, stream>>>(ws16, bo, x, out);
}

// Round 12
// 106.840 us; speedup vs baseline: 1.8248x; 1.0088x over previous
//
#include <hip/hip_runtime.h>

typedef __bf16 bf16_t;
typedef bf16_t bf16x8 __attribute__((ext_vector_type(8)));
typedef float f32x4 __attribute__((ext_vector_type(4)));

#define MFMA16(a,b,c) __builtin_amdgcn_mfma_f32_16x16x32_bf16((a),(b),(c),0,0,0)

#define GLOAD_LDS16(gsrc, ldst) \
  __builtin_amdgcn_global_load_lds((const __attribute__((address_space(1))) unsigned int*)(gsrc), \
                                   (__attribute__((address_space(3))) unsigned int*)(ldst), 16, 0, 0)

__device__ __forceinline__ unsigned short f2bf(float f){
  unsigned int u = __builtin_bit_cast(unsigned int, f);
  u = (u + 0x7FFFu + ((u >> 16) & 1u)) >> 16;
  return (unsigned short)u;
}
__device__ __forceinline__ float bf2f(unsigned short u){
  return __builtin_bit_cast(float, (unsigned int)u << 16);
}
__device__ __forceinline__ ushort4 pk4(f32x4 v){
  union { __bf16 b[4]; ushort4 u; } r;
  r.b[0]=(__bf16)v[0]; r.b[1]=(__bf16)v[1]; r.b[2]=(__bf16)v[2]; r.b[3]=(__bf16)v[3];
  return r.u;
}
__device__ __forceinline__ unsigned cvtpk(float lo, float hi){
  unsigned r; asm("v_cvt_pk_bf16_f32 %0, %1, %2" : "=v"(r) : "v"(lo), "v"(hi)); return r;
}
__device__ __forceinline__ float max3f(float a, float b, float c){
  float r; asm("v_max3_f32 %0, %1, %2, %3" : "=v"(r) : "v"(a), "v"(b), "v"(c)); return r;
}

// KI: k-interleave within 64-elem segment (for Q/K/V consumed by attention).
__device__ __forceinline__ int KI(int d){   // d 4-aligned
  int gi = (d >> 2) & 15;
  int pos = (gi & 8) | ((gi & 3) << 1) | ((gi >> 2) & 1);
  return (d & ~63) | (pos << 2);
}

// Blocked fragment layout for GEMM operands [R][256]:
// wave fragment load at (rowbase*256 + ks*16 + lq*32 + lg*8) is contiguous 1KB.
__device__ __forceinline__ int BL256(int r, int c){
  return ((r >> 4) << 12) + (((c >> 5)) << 9) + ((r & 15) << 5)
       + (((c & 15) >> 2) << 3) + (((c >> 4) & 1) << 2) + (c & 3);
}

constexpr int BN = 2;
constexpr int CC = 256;
constexpr int S  = 4096;
constexpr int HH = 4;
constexpr int DD = 64;

constexpr size_t OFF_WQ = 0;
constexpr size_t OFF_WK = 65536;
constexpr size_t OFF_WV = 131072;
constexpr size_t OFF_WO = 196608;
constexpr size_t OFF_NY = 262144;                      // blocked [p][c]
constexpr size_t OFF_NX = OFF_NY + (size_t)BN*S*CC;    // blocked [p][c]
constexpr size_t OFF_Q  = OFF_NX + (size_t)BN*S*CC;    // [b][h][p][d~KI] (pre-scaled 0.125*log2e)
constexpr size_t OFF_K  = OFF_Q  + (size_t)BN*S*CC;    // [b][h][p][d~KI]
constexpr size_t OFF_V  = OFF_K  + (size_t)BN*S*CC;    // [b][c][p~KI]
constexpr size_t OFF_AO = OFF_V  + (size_t)BN*S*CC;    // (dead after qkv: reused as PACC ch2)
// Attention partials (3 t-chunks): ch0->NY, ch1->NX, ch2->AO (dead after qkv_gemm).
// ML [3][8][4096][2] f32 overlays OFF_Q (clobbers Q[bh0..1.5]). SAFE: attn grid (768)
// is fully co-resident (3 blocks/CU via __launch_bounds__(256,3)); every block reads Q
// in its prologue long before any epilogue ML write. qkv rewrites Q each call.
__device__ __forceinline__ unsigned short* pacc_base(unsigned short* ws, int ch){
  return ws + (ch == 0 ? OFF_NY : (ch == 1 ? OFF_NX : OFF_AO));
}

// ---------------- fused weight-convert + GroupNorm ----------------
__global__ __launch_bounds__(256) void prep_k(const float* __restrict__ x, const float* __restrict__ y,
    const float* __restrict__ g1, const float* __restrict__ b1,
    const float* __restrict__ g2, const float* __restrict__ b2,
    const float* __restrict__ wq, const float* __restrict__ wk,
    const float* __restrict__ wv, const float* __restrict__ wo,
    unsigned short* __restrict__ ws)
{
  __shared__ float red[8];
  __shared__ float mv[2];
  const int tid = threadIdx.x;
  const int bid = blockIdx.x;

  if (bid >= 128){
    const int idx = (bid - 128)*256 + tid;
    const int m = idx >> 14;
    const int off = (idx & 16383) << 2;
    const float* src = (m==0) ? wq : (m==1) ? wk : (m==2) ? wv : wo;
    float4 v = *(const float4*)(src + off);
    ushort4 r; r.x=f2bf(v.x); r.y=f2bf(v.y); r.z=f2bf(v.z); r.w=f2bf(v.w);
    const int o = off >> 8, c = off & 255;
    *(ushort4*)(ws + (size_t)m*65536 + BL256(o, c)) = r;
    return;
  }

  const int tsel = bid >> 6;
  const int rem  = bid & 63;
  const int b = rem >> 5, g = rem & 31;
  const float* in = (tsel ? y : x) + ((size_t)b*CC + g*8)*S;
  unsigned short* outp = ws + (tsel ? OFF_NY : OFF_NX) + (size_t)b*S*CC;
  const int j = g & 3;
  const int gk = (g >> 2) * 512;
  const int posA = (j & 1)*16 + (j >> 1)*4;
  const int posB = posA + 8;
  const float* gamma = (tsel ? g2 : g1) + g*8;
  const float* beta  = (tsel ? b2 : b1) + g*8;

  float s = 0.f, ss = 0.f;
  #pragma unroll
  for (int ci = 0; ci < 8; ci++){
    const float4* row = (const float4*)(in + (size_t)ci*S);
    #pragma unroll
    for (int i = 0; i < 4; i++){
      float4 v = row[tid + i*256];
      s  += v.x + v.y + v.z + v.w;
      ss += v.x*v.x + v.y*v.y + v.z*v.z + v.w*v.w;
    }
  }
  #pragma unroll
  for (int off = 1; off < 64; off <<= 1){
    s  += __shfl_xor(s,  off);
    ss += __shfl_xor(ss, off);
  }
  const int wave = tid >> 6, lane = tid & 63;
  if (lane == 0){ red[wave] = s; red[4+wave] = ss; }
  __syncthreads();
  if (tid == 0){
    float S1 = red[0]+red[1]+red[2]+red[3];
    float S2 = red[4]+red[5]+red[6]+red[7];
    const float invn = 1.0f/32768.0f;
    float mean = S1*invn;
    float var  = S2*invn - mean*mean;
    mv[0] = mean; mv[1] = rsqrtf(var + 1e-6f);
  }
  __syncthreads();
  const float mean = mv[0], rstd = mv[1];
  float sc[8], sh[8];
  #pragma unroll
  for (int ci = 0; ci < 8; ci++){ sc[ci] = rstd*gamma[ci]; sh[ci] = beta[ci] - mean*sc[ci]; }
  for (int i = 0; i < 16; i++){
    const int p = tid + i*256;
    const int base = ((p >> 4) << 12) + gk + ((p & 15) << 5);
    ushort4 a0, a1;
    a0.x = f2bf(in[0*S+p]*sc[0]+sh[0]);
    a0.y = f2bf(in[1*S+p]*sc[1]+sh[1]);
    a0.z = f2bf(in[2*S+p]*sc[2]+sh[2]);
    a0.w = f2bf(in[3*S+p]*sc[3]+sh[3]);
    a1.x = f2bf(in[4*S+p]*sc[4]+sh[4]);
    a1.y = f2bf(in[5*S+p]*sc[5]+sh[5]);
    a1.z = f2bf(in[6*S+p]*sc[6]+sh[6]);
    a1.w = f2bf(in[7*S+p]*sc[7]+sh[7]);
    *(ushort4*)(outp + base + posA) = a0;
    *(ushort4*)(outp + base + posB) = a1;
  }
}

// ---------------- Q/K/V projection GEMMs, 768 blocks (3/CU) ----------------
__global__ __launch_bounds__(256, 3) void qkv_gemm(unsigned short* __restrict__ ws,
    const float* __restrict__ bq, const float* __restrict__ bk, const float* __restrict__ bv)
{
  const int tid = threadIdx.x;
  const int lane = tid & 63, wave = tid >> 6;
  const int lq = lane & 15, lg = lane >> 4;
  const int lofs = lq*32 + lg*8;
  const int bid = blockIdx.x;

  if (bid < 512){
    const int inst2 = bid >> 7;             // 0..3
    const int which = inst2 >> 1;           // 0=Q,1=K
    const int b = inst2 & 1;
    const int tile = bid & 127;
    const int mtile = tile & 3;
    const int ntile = tile >> 2;
    const int mbase = mtile*64 + (wave>>1)*32;
    const int nbase = ntile*128 + (wave&1)*64;
    const unsigned short* Amat = ws + (which==0 ? OFF_WQ : OFF_WK);
    const unsigned short* Bmat = ws + (which==0 ? OFF_NY : OFF_NX) + (size_t)b*S*CC;

    f32x4 acc[2][4];
    #pragma unroll
    for (int i = 0; i < 2; i++)
      #pragma unroll
      for (int j = 0; j < 4; j++)
        acc[i][j] = (f32x4){0.f,0.f,0.f,0.f};

    const unsigned short* Arow = Amat + (size_t)mbase*CC + lofs;
    const unsigned short* Brow = Bmat + (size_t)nbase*CC + lofs;
    for (int ks = 0; ks < CC; ks += 32) {
      bf16x8 af[2], bfr[4];
      #pragma unroll
      for (int mt = 0; mt < 2; mt++)
        af[mt] = *(const bf16x8*)(Arow + mt*16*CC + ks*16);
      #pragma unroll
      for (int nt = 0; nt < 4; nt++)
        bfr[nt] = *(const bf16x8*)(Brow + nt*16*CC + ks*16);
      #pragma unroll
      for (int mt = 0; mt < 2; mt++)
        #pragma unroll
        for (int nt = 0; nt < 4; nt++)
          acc[mt][nt] = MFMA16(af[mt], bfr[nt], acc[mt][nt]);
    }

    const float* bias = (which==0) ? bq : bk;
    const float scl = (which==0) ? 0.125f*1.44269504089f : 1.0f;
    unsigned short* Outp = ws + (which==0 ? OFF_Q : OFF_K) + (size_t)b*HH*S*DD;
    #pragma unroll
    for (int mt = 0; mt < 2; mt++){
      const int o = mbase + mt*16 + lg*4;
      const float4 bb = *(const float4*)(bias + o);
      const int hd = o >> 6, db = KI(o & 63);
      #pragma unroll
      for (int nt = 0; nt < 4; nt++){
        const int p = nbase + nt*16 + lq;
        f32x4 v = acc[mt][nt];
        ushort4 r;
        r.x = f2bf((v[0]+bb.x)*scl); r.y = f2bf((v[1]+bb.y)*scl);
        r.z = f2bf((v[2]+bb.z)*scl); r.w = f2bf((v[3]+bb.w)*scl);
        *(ushort4*)(Outp + ((size_t)hd*S + p)*DD + db) = r;
      }
    }
  } else {
    const int r0 = bid - 512;
    const int b = r0 >> 7;
    const int tile = r0 & 127;
    const int mtile = tile >> 2;
    const int ntile = tile & 3;
    const int mbase = mtile*128 + (wave>>1)*64;
    const int nbase = ntile*64 + (wave&1)*32;
    const unsigned short* Amat = ws + OFF_NX + (size_t)b*S*CC;
    const unsigned short* Bmat = ws + OFF_WV;

    f32x4 acc[4][2];
    #pragma unroll
    for (int i = 0; i < 4; i++)
      #pragma unroll
      for (int j = 0; j < 2; j++)
        acc[i][j] = (f32x4){0.f,0.f,0.f,0.f};

    const unsigned short* Arow = Amat + (size_t)mbase*CC + lofs;
    const unsigned short* Brow = Bmat + (size_t)nbase*CC + lofs;
    for (int ks = 0; ks < CC; ks += 32) {
      bf16x8 af[4], bfr[2];
      #pragma unroll
      for (int mt = 0; mt < 4; mt++)
        af[mt] = *(const bf16x8*)(Arow + mt*16*CC + ks*16);
      #pragma unroll
      for (int nt = 0; nt < 2; nt++)
        bfr[nt] = *(const bf16x8*)(Brow + nt*16*CC + ks*16);
      #pragma unroll
      for (int mt = 0; mt < 4; mt++)
        #pragma unroll
        for (int nt = 0; nt < 2; nt++)
          acc[mt][nt] = MFMA16(af[mt], bfr[nt], acc[mt][nt]);
    }

    unsigned short* Outp = ws + OFF_V + (size_t)b*CC*S;
    #pragma unroll
    for (int nt = 0; nt < 2; nt++){
      const int o = nbase + nt*16 + lq;
      const float bb = bv[o];
      #pragma unroll
      for (int mt = 0; mt < 4; mt++){
        const int p = mbase + mt*16 + lg*4;
        f32x4 v = acc[mt][nt];
        ushort4 r;
        r.x = f2bf(v[0]+bb); r.y = f2bf(v[1]+bb);
        r.z = f2bf(v[2]+bb); r.w = f2bf(v[3]+bb);
        *(ushort4*)(Outp + (size_t)o*S + KI(p)) = r;
      }
    }
  }
}

// ---------------- flash attention: 3-way split-t, 3 blocks/CU, VALU diet ----------------
// grid 768: bid = ((ch*32 + qblk)*8) + bh. 4 waves x 32 q = 128 q per block.
// K/V LDS [64][64] double-buffered (0-conflict layout), global_load_lds staging.
// Max tree via v_max3_f32; P packed via v_cvt_pk_bf16_f32 (both validated in R9's
// passing run). Defer-max check uses the always-reduced tm (R8/R11 structure).
// l accumulated via MFMA with all-ones A-operand.
__global__ __launch_bounds__(256, 3) void attn_k(unsigned short* __restrict__ ws)
{
  __shared__ __align__(1024) char lds[32768];   // K: 0/8192, V: 16384/24576
  const int tid = threadIdx.x;
  const int lane = tid & 63, wave = tid >> 6;
  const int lq = lane & 15, lg = lane >> 4;
  const int rsw = (lq & 7) << 4;
  const int bid = blockIdx.x;
  const int bh = bid & 7;
  const int rest = bid >> 3;                // 0..95
  const int qblk = rest & 31;
  const int ch = rest >> 5;                 // 0..2
  const int tBeg = ch*1344 + (ch ? 64 : 0);
  const int tEnd = tBeg + 1344 + (ch ? 0 : 64);
  const unsigned short* Qp = ws + OFF_Q + (size_t)bh*S*DD;
  const unsigned short* Kp = ws + OFF_K + (size_t)bh*S*DD;
  const int b = bh >> 2, h = bh & 3;
  const unsigned short* Vp = ws + OFF_V + ((size_t)b*CC + h*DD)*S;
  const int qbw = qblk*128 + wave*32;

  bf16x8 qf[2][2];
  #pragma unroll
  for (int f = 0; f < 2; f++)
    #pragma unroll
    for (int hh = 0; hh < 2; hh++)
      qf[f][hh] = *(const bf16x8*)(Qp + (size_t)(qbw + f*16 + lq)*DD + hh*32 + lg*8);

  bf16x8 ones;
  #pragma unroll
  for (int i = 0; i < 8; i++) ones[i] = (__bf16)1.0f;

  const int csel = ((lane & 7) ^ ((lane >> 3) & 7)) * 8;
  const int srow = wave*16 + (lane >> 3);
  const int kofs0 = lq*128 + ((lg*16) ^ rsw);
  const int kofs1 = kofs0 ^ 64;

  f32x4 acc[4][2];
  #pragma unroll
  for (int i = 0; i < 4; i++)
    #pragma unroll
    for (int f = 0; f < 2; f++)
      acc[i][f] = (f32x4){0.f,0.f,0.f,0.f};
  f32x4 accL[2] = {(f32x4){0.f,0.f,0.f,0.f}, (f32x4){0.f,0.f,0.f,0.f}};
  float mr[2] = {-1e30f, -1e30f};

  #pragma unroll
  for (int j = 0; j < 2; j++){
    const int row = srow + j*8;
    GLOAD_LDS16(Kp + (size_t)(tBeg + row)*DD + csel, lds + wave*2048 + j*1024);
    GLOAD_LDS16(Vp + (size_t)row*S + tBeg + csel,    lds + 16384 + wave*2048 + j*1024);
  }
  __syncthreads();

  int cur = 0;
  for (int t0 = tBeg; t0 < tEnd; t0 += 64){
    const char* kb = lds + cur*8192;
    const char* vb = lds + 16384 + cur*8192;
    if (t0 + 64 < tEnd){
      char* kn = lds + (cur^1)*8192;
      char* vn = lds + 16384 + (cur^1)*8192;
      #pragma unroll
      for (int j = 0; j < 2; j++){
        const int row = srow + j*8;
        GLOAD_LDS16(Kp + (size_t)(t0 + 64 + row)*DD + csel, kn + wave*2048 + j*1024);
        GLOAD_LDS16(Vp + (size_t)row*S + (t0 + 64) + csel,  vn + wave*2048 + j*1024);
      }
    }
    bf16x8 kf[4][2];
    #pragma unroll
    for (int mt = 0; mt < 4; mt++){
      kf[mt][0] = *(const bf16x8*)(kb + mt*2048 + kofs0);
      kf[mt][1] = *(const bf16x8*)(kb + mt*2048 + kofs1);
    }
    f32x4 st[2][4];
    #pragma unroll
    for (int f = 0; f < 2; f++)
      #pragma unroll
      for (int mt = 0; mt < 4; mt++){
        f32x4 z = (f32x4){0.f,0.f,0.f,0.f};
        z = MFMA16(kf[mt][0], qf[f][0], z);
        z = MFMA16(kf[mt][1], qf[f][1], z);
        st[f][mt] = z;
      }
    bf16x8 vf[4][2];
    #pragma unroll
    for (int dt = 0; dt < 4; dt++){
      vf[dt][0] = *(const bf16x8*)(vb + dt*2048 + kofs0);
      vf[dt][1] = *(const bf16x8*)(vb + dt*2048 + kofs1);
    }
    // online softmax (exp2 domain), defer-max THR=8; max tree via v_max3
    float tmv[2];
    #pragma unroll
    for (int f = 0; f < 2; f++){
      float m1 = max3f(st[f][0][0], st[f][0][1], st[f][0][2]);
      float m2 = max3f(st[f][0][3], st[f][1][0], st[f][1][1]);
      float m3 = max3f(st[f][1][2], st[f][1][3], st[f][2][0]);
      float m4 = max3f(st[f][2][1], st[f][2][2], st[f][2][3]);
      float m5 = max3f(st[f][3][0], st[f][3][1], st[f][3][2]);
      float tm = fmaxf(fmaxf(max3f(m1, m2, m3), fmaxf(m4, m5)), st[f][3][3]);
      tm = fmaxf(tm, __shfl_xor(tm, 16));
      tm = fmaxf(tm, __shfl_xor(tm, 32));
      tmv[f] = tm;
    }
    if (!__all((tmv[0] <= mr[0] + 8.f) && (tmv[1] <= mr[1] + 8.f))){
      #pragma unroll
      for (int f = 0; f < 2; f++){
        const float mnew = fmaxf(mr[f], tmv[f]);
        const float c = __builtin_amdgcn_exp2f(mr[f] - mnew);
        #pragma unroll
        for (int dt = 0; dt < 4; dt++)
          #pragma unroll
          for (int r = 0; r < 4; r++)
            acc[dt][f][r] *= c;
        #pragma unroll
        for (int r = 0; r < 4; r++) accL[f][r] *= c;
        mr[f] = mnew;
      }
    }
    union PU { bf16x8 v; unsigned u[4]; } p0[2], p1[2];
    #pragma unroll
    for (int f = 0; f < 2; f++){
      #pragma unroll
      for (int mt = 0; mt < 4; mt++){
        float e0 = __builtin_amdgcn_exp2f(st[f][mt][0] - mr[f]);
        float e1 = __builtin_amdgcn_exp2f(st[f][mt][1] - mr[f]);
        float e2 = __builtin_amdgcn_exp2f(st[f][mt][2] - mr[f]);
        float e3 = __builtin_amdgcn_exp2f(st[f][mt][3] - mr[f]);
        if (mt < 2){ p0[f].u[mt*2] = cvtpk(e0, e1); p0[f].u[mt*2+1] = cvtpk(e2, e3); }
        else       { p1[f].u[(mt-2)*2] = cvtpk(e0, e1); p1[f].u[(mt-2)*2+1] = cvtpk(e2, e3); }
      }
    }
    // PV + l-sum (ones-A MFMA)
    #pragma unroll
    for (int dt = 0; dt < 4; dt++)
      #pragma unroll
      for (int f = 0; f < 2; f++){
        f32x4 a = acc[dt][f];
        a = MFMA16(vf[dt][0], p0[f].v, a);
        a = MFMA16(vf[dt][1], p1[f].v, a);
        acc[dt][f] = a;
      }
    #pragma unroll
    for (int f = 0; f < 2; f++){
      accL[f] = MFMA16(ones, p0[f].v, accL[f]);
      accL[f] = MFMA16(ones, p1[f].v, accL[f]);
    }
    __syncthreads();
    cur ^= 1;
  }

  // epilogue: unnormalized partials (PACC bf16) + m/l
  unsigned short* PA = pacc_base(ws, ch) + (size_t)bh*S*DD;
  float* ML = (float*)(ws + OFF_Q) + ((size_t)ch*8 + bh)*S*2;
  #pragma unroll
  for (int f = 0; f < 2; f++){
    const int q = qbw + f*16 + lq;
    #pragma unroll
    for (int dt = 0; dt < 4; dt++)
      *(ushort4*)(PA + (size_t)q*DD + dt*16 + lg*4) = pk4(acc[dt][f]);
    if (lg == 0){
      ML[(size_t)q*2]   = mr[f];
      ML[(size_t)q*2+1] = accL[f][0];
    }
  }
}

// ---------------- output projection: merge + GEMM + residual, 512 blocks (2/CU) ----------------
// tile 64q x 64o; wave = 32q x 32o.
__global__ __launch_bounds__(256, 2) void outproj_k(unsigned short* __restrict__ ws,
    const float* __restrict__ bo, const float* __restrict__ x, float* __restrict__ out)
{
  __shared__ unsigned short ldsA[16384];    // 64 x 256 blocked, 32KB
  __shared__ float wtab[64][4][3];
  const int tid = threadIdx.x;
  const int lane = tid & 63, wave = tid >> 6;
  const int lq = lane & 15, lg = lane >> 4;
  const int lofs = lq*32 + lg*8;
  const int bid = blockIdx.x;
  const int b = bid >> 8;
  const int r0 = bid & 255;
  const int mtile = r0 >> 2;                // 64 q-tiles of 64
  const int ntile = r0 & 3;                 // 4 o-tiles of 64
  const int qg = mtile*64;

  // phase 1: merge weights per (q,h)
  {
    const int q = tid >> 2, h = tid & 3;
    const float* MLb = (const float*)(ws + OFF_Q);
    float m[3], l[3];
    #pragma unroll
    for (int c = 0; c < 3; c++){
      const float* p = MLb + (((size_t)c*8 + b*4 + h)*S + (qg + q))*2;
      m[c] = p[0]; l[c] = p[1];
    }
    const float M = fmaxf(m[0], fmaxf(m[1], m[2]));
    const float w0 = __builtin_amdgcn_exp2f(m[0] - M);
    const float w1 = __builtin_amdgcn_exp2f(m[1] - M);
    const float w2 = __builtin_amdgcn_exp2f(m[2] - M);
    const float inv = 1.0f / (w0*l[0] + w1*l[1] + w2*l[2]);
    wtab[q][h][0] = w0*inv; wtab[q][h][1] = w1*inv; wtab[q][h][2] = w2*inv;
  }
  __syncthreads();

  // phase 2: merge 64q x 256c into blocked LDS A-tile
  #pragma unroll
  for (int it = 0; it < 16; it++){
    const int w = it*256 + tid;
    const int q = w >> 6, cq = w & 63;
    const int h = cq >> 4, d = (cq & 15)*4;
    const size_t po = ((size_t)(b*4 + h)*S + (qg + q))*DD + d;
    const ushort4 a0 = *(const ushort4*)(ws + OFF_NY + po);
    const ushort4 a1 = *(const ushort4*)(ws + OFF_NX + po);
    const ushort4 a2 = *(const ushort4*)(ws + OFF_AO + po);
    const float w0 = wtab[q][h][0], w1 = wtab[q][h][1], w2 = wtab[q][h][2];
    f32x4 v;
    v[0] = bf2f(a0.x)*w0 + bf2f(a1.x)*w1 + bf2f(a2.x)*w2;
    v[1] = bf2f(a0.y)*w0 + bf2f(a1.y)*w1 + bf2f(a2.y)*w2;
    v[2] = bf2f(a0.z)*w0 + bf2f(a1.z)*w1 + bf2f(a2.z)*w2;
    v[3] = bf2f(a0.w)*w0 + bf2f(a1.w)*w1 + bf2f(a2.w)*w2;
    *(ushort4*)(ldsA + BL256(q, cq*4)) = pk4(v);
  }
  __syncthreads();

  // phase 3: GEMM (A from LDS, B=WO from global) + bias + residual
  const int mbase = (wave>>1)*32;           // local q base
  const int nbase = ntile*64 + (wave&1)*32; // global o base
  f32x4 acc[2][2];
  #pragma unroll
  for (int i = 0; i < 2; i++)
    #pragma unroll
    for (int j = 0; j < 2; j++)
      acc[i][j] = (f32x4){0.f,0.f,0.f,0.f};
  const unsigned short* Arow = ldsA + (size_t)mbase*CC + lofs;
  const unsigned short* Brow = ws + OFF_WO + (size_t)nbase*CC + lofs;
  for (int ks = 0; ks < CC; ks += 32) {
    bf16x8 af[2], bfr[2];
    #pragma unroll
    for (int mt = 0; mt < 2; mt++)
      af[mt] = *(const bf16x8*)(Arow + mt*16*CC + ks*16);
    #pragma unroll
    for (int nt = 0; nt < 2; nt++)
      bfr[nt] = *(const bf16x8*)(Brow + nt*16*CC + ks*16);
    #pragma unroll
    for (int mt = 0; mt < 2; mt++)
      #pragma unroll
      for (int nt = 0; nt < 2; nt++)
        acc[mt][nt] = MFMA16(af[mt], bfr[nt], acc[mt][nt]);
  }
  #pragma unroll
  for (int nt = 0; nt < 2; nt++){
    const int o = nbase + nt*16 + lq;
    const float bb = bo[o];
    #pragma unroll
    for (int mt = 0; mt < 2; mt++){
      const int p = qg + mbase + mt*16 + lg*4;
      const size_t idx = ((size_t)b*CC + o)*S + p;
      const float4 xr = *(const float4*)(x + idx);
      f32x4 v = acc[mt][nt];
      float4 r; r.x = v[0]+bb+xr.x; r.y = v[1]+bb+xr.y; r.z = v[2]+bb+xr.z; r.w = v[3]+bb+xr.w;
      *(float4*)(out + idx) = r;
    }
  }
}

extern "C" void kernel_launch(void* const* d_in, const int* in_sizes, int n_in,
                              void* d_out, int out_size, void* d_ws, size_t ws_size,
                              hipStream_t stream) {
  const float* x  = (const float*)d_in[0];
  const float* y  = (const float*)d_in[1];
  const float* g1 = (const float*)d_in[2];
  const float* b1 = (const float*)d_in[3];
  const float* g2 = (const float*)d_in[4];
  const float* b2 = (const float*)d_in[5];
  const float* wq = (const float*)d_in[6];
  const float* bq = (const float*)d_in[7];
  const float* wk = (const float*)d_in[8];
  const float* bk = (const float*)d_in[9];
  const float* wv = (const float*)d_in[10];
  const float* bv = (const float*)d_in[11];
  const float* wo = (const float*)d_in[12];
  const float* bo = (const float*)d_in[13];
  float* out = (float*)d_out;
  unsigned short* ws16 = (unsigned short*)d_ws;

  prep_k   <<<384, 256, 0, stream>>>(x, y, g1, b1, g2, b2, wq, wk, wv, wo, ws16);
  qkv_gemm <<<768, 256, 0, stream>>>(ws16, bq, bk, bv);
  attn_k   <<<768, 256, 0, stream>>>(ws16);
  outproj_k<<<512, 256, 0, stream>>>(ws16, bo, x, out);
}

// Round 14
// 105.660 us; speedup vs baseline: 1.8452x; 1.0112x over previous
//
#include <hip/hip_runtime.h>

typedef __bf16 bf16_t;
typedef bf16_t bf16x8 __attribute__((ext_vector_type(8)));
typedef float f32x4 __attribute__((ext_vector_type(4)));

#define MFMA16(a,b,c) __builtin_amdgcn_mfma_f32_16x16x32_bf16((a),(b),(c),0,0,0)

#define GLOAD_LDS16(gsrc, ldst) \
  __builtin_amdgcn_global_load_lds((const __attribute__((address_space(1))) unsigned int*)(gsrc), \
                                   (__attribute__((address_space(3))) unsigned int*)(ldst), 16, 0, 0)

__device__ __forceinline__ unsigned short f2bf(float f){
  unsigned int u = __builtin_bit_cast(unsigned int, f);
  u = (u + 0x7FFFu + ((u >> 16) & 1u)) >> 16;
  return (unsigned short)u;
}
__device__ __forceinline__ float bf2f(unsigned short u){
  return __builtin_bit_cast(float, (unsigned int)u << 16);
}
__device__ __forceinline__ ushort4 pk4(f32x4 v){
  union { __bf16 b[4]; ushort4 u; } r;
  r.b[0]=(__bf16)v[0]; r.b[1]=(__bf16)v[1]; r.b[2]=(__bf16)v[2]; r.b[3]=(__bf16)v[3];
  return r.u;
}
__device__ __forceinline__ unsigned cvtpk(float lo, float hi){
  unsigned r; asm("v_cvt_pk_bf16_f32 %0, %1, %2" : "=v"(r) : "v"(lo), "v"(hi)); return r;
}
__device__ __forceinline__ float max3f(float a, float b, float c){
  float r; asm("v_max3_f32 %0, %1, %2, %3" : "=v"(r) : "v"(a), "v"(b), "v"(c)); return r;
}

// KI: k-interleave within 64-elem segment (for Q/K/V consumed by attention).
__device__ __forceinline__ int KI(int d){   // d 4-aligned
  int gi = (d >> 2) & 15;
  int pos = (gi & 8) | ((gi & 3) << 1) | ((gi >> 2) & 1);
  return (d & ~63) | (pos << 2);
}

// Blocked fragment layout for GEMM operands [R][256]:
// wave fragment load at (rowbase*256 + ks*16 + lq*32 + lg*8) is contiguous 1KB.
__device__ __forceinline__ int BL256(int r, int c){
  return ((r >> 4) << 12) + (((c >> 5)) << 9) + ((r & 15) << 5)
       + (((c & 15) >> 2) << 3) + (((c >> 4) & 1) << 2) + (c & 3);
}

constexpr int BN = 2;
constexpr int CC = 256;
constexpr int S  = 4096;
constexpr int HH = 4;
constexpr int DD = 64;

constexpr size_t OFF_WQ = 0;
constexpr size_t OFF_WK = 65536;
constexpr size_t OFF_WV = 131072;
constexpr size_t OFF_WO = 196608;
constexpr size_t OFF_NY = 262144;                      // blocked [p][c]
constexpr size_t OFF_NX = OFF_NY + (size_t)BN*S*CC;    // blocked [p][c]
constexpr size_t OFF_Q  = OFF_NX + (size_t)BN*S*CC;    // [b][h][p][d~KI] (pre-scaled 0.125*log2e)
constexpr size_t OFF_K  = OFF_Q  + (size_t)BN*S*CC;    // [b][h][p][d~KI]
constexpr size_t OFF_V  = OFF_K  + (size_t)BN*S*CC;    // [b][c][p~KI]
constexpr size_t OFF_AO = OFF_V  + (size_t)BN*S*CC;    // (dead after qkv: reused as PACC ch2)
// Attention partials (3 t-chunks): ch0->NY, ch1->NX, ch2->AO (dead after qkv_gemm).
// ML [3][8][4096][2] f32 overlays OFF_Q (clobbers Q[bh0..1.5]). SAFE: attn grid (768)
// is fully co-resident (3 blocks/CU via __launch_bounds__(256,3)); every block reads Q
// in its prologue long before any epilogue ML write. qkv rewrites Q each call.
__device__ __forceinline__ unsigned short* pacc_base(unsigned short* ws, int ch){
  return ws + (ch == 0 ? OFF_NY : (ch == 1 ? OFF_NX : OFF_AO));
}

// ---------------- fused weight-convert + GroupNorm ----------------
__global__ __launch_bounds__(256) void prep_k(const float* __restrict__ x, const float* __restrict__ y,
    const float* __restrict__ g1, const float* __restrict__ b1,
    const float* __restrict__ g2, const float* __restrict__ b2,
    const float* __restrict__ wq, const float* __restrict__ wk,
    const float* __restrict__ wv, const float* __restrict__ wo,
    unsigned short* __restrict__ ws)
{
  __shared__ float red[8];
  __shared__ float mv[2];
  const int tid = threadIdx.x;
  const int bid = blockIdx.x;

  if (bid >= 128){
    const int idx = (bid - 128)*256 + tid;
    const int m = idx >> 14;
    const int off = (idx & 16383) << 2;
    const float* src = (m==0) ? wq : (m==1) ? wk : (m==2) ? wv : wo;
    float4 v = *(const float4*)(src + off);
    ushort4 r; r.x=f2bf(v.x); r.y=f2bf(v.y); r.z=f2bf(v.z); r.w=f2bf(v.w);
    const int o = off >> 8, c = off & 255;
    *(ushort4*)(ws + (size_t)m*65536 + BL256(o, c)) = r;
    return;
  }

  const int tsel = bid >> 6;
  const int rem  = bid & 63;
  const int b = rem >> 5, g = rem & 31;
  const float* in = (tsel ? y : x) + ((size_t)b*CC + g*8)*S;
  unsigned short* outp = ws + (tsel ? OFF_NY : OFF_NX) + (size_t)b*S*CC;
  const int j = g & 3;
  const int gk = (g >> 2) * 512;
  const int posA = (j & 1)*16 + (j >> 1)*4;
  const int posB = posA + 8;
  const float* gamma = (tsel ? g2 : g1) + g*8;
  const float* beta  = (tsel ? b2 : b1) + g*8;

  float s = 0.f, ss = 0.f;
  #pragma unroll
  for (int ci = 0; ci < 8; ci++){
    const float4* row = (const float4*)(in + (size_t)ci*S);
    #pragma unroll
    for (int i = 0; i < 4; i++){
      float4 v = row[tid + i*256];
      s  += v.x + v.y + v.z + v.w;
      ss += v.x*v.x + v.y*v.y + v.z*v.z + v.w*v.w;
    }
  }
  #pragma unroll
  for (int off = 1; off < 64; off <<= 1){
    s  += __shfl_xor(s,  off);
    ss += __shfl_xor(ss, off);
  }
  const int wave = tid >> 6, lane = tid & 63;
  if (lane == 0){ red[wave] = s; red[4+wave] = ss; }
  __syncthreads();
  if (tid == 0){
    float S1 = red[0]+red[1]+red[2]+red[3];
    float S2 = red[4]+red[5]+red[6]+red[7];
    const float invn = 1.0f/32768.0f;
    float mean = S1*invn;
    float var  = S2*invn - mean*mean;
    mv[0] = mean; mv[1] = rsqrtf(var + 1e-6f);
  }
  __syncthreads();
  const float mean = mv[0], rstd = mv[1];
  float sc[8], sh[8];
  #pragma unroll
  for (int ci = 0; ci < 8; ci++){ sc[ci] = rstd*gamma[ci]; sh[ci] = beta[ci] - mean*sc[ci]; }
  for (int i = 0; i < 16; i++){
    const int p = tid + i*256;
    const int base = ((p >> 4) << 12) + gk + ((p & 15) << 5);
    ushort4 a0, a1;
    a0.x = f2bf(in[0*S+p]*sc[0]+sh[0]);
    a0.y = f2bf(in[1*S+p]*sc[1]+sh[1]);
    a0.z = f2bf(in[2*S+p]*sc[2]+sh[2]);
    a0.w = f2bf(in[3*S+p]*sc[3]+sh[3]);
    a1.x = f2bf(in[4*S+p]*sc[4]+sh[4]);
    a1.y = f2bf(in[5*S+p]*sc[5]+sh[5]);
    a1.z = f2bf(in[6*S+p]*sc[6]+sh[6]);
    a1.w = f2bf(in[7*S+p]*sc[7]+sh[7]);
    *(ushort4*)(outp + base + posA) = a0;
    *(ushort4*)(outp + base + posB) = a1;
  }
}

// ---------------- Q/K/V projection GEMMs, 768 blocks (3/CU) ----------------
__global__ __launch_bounds__(256, 3) void qkv_gemm(unsigned short* __restrict__ ws,
    const float* __restrict__ bq, const float* __restrict__ bk, const float* __restrict__ bv)
{
  const int tid = threadIdx.x;
  const int lane = tid & 63, wave = tid >> 6;
  const int lq = lane & 15, lg = lane >> 4;
  const int lofs = lq*32 + lg*8;
  const int bid = blockIdx.x;

  if (bid < 512){
    const int inst2 = bid >> 7;             // 0..3
    const int which = inst2 >> 1;           // 0=Q,1=K
    const int b = inst2 & 1;
    const int tile = bid & 127;
    const int mtile = tile & 3;
    const int ntile = tile >> 2;
    const int mbase = mtile*64 + (wave>>1)*32;
    const int nbase = ntile*128 + (wave&1)*64;
    const unsigned short* Amat = ws + (which==0 ? OFF_WQ : OFF_WK);
    const unsigned short* Bmat = ws + (which==0 ? OFF_NY : OFF_NX) + (size_t)b*S*CC;

    f32x4 acc[2][4];
    #pragma unroll
    for (int i = 0; i < 2; i++)
      #pragma unroll
      for (int j = 0; j < 4; j++)
        acc[i][j] = (f32x4){0.f,0.f,0.f,0.f};

    const unsigned short* Arow = Amat + (size_t)mbase*CC + lofs;
    const unsigned short* Brow = Bmat + (size_t)nbase*CC + lofs;
    for (int ks = 0; ks < CC; ks += 32) {
      bf16x8 af[2], bfr[4];
      #pragma unroll
      for (int mt = 0; mt < 2; mt++)
        af[mt] = *(const bf16x8*)(Arow + mt*16*CC + ks*16);
      #pragma unroll
      for (int nt = 0; nt < 4; nt++)
        bfr[nt] = *(const bf16x8*)(Brow + nt*16*CC + ks*16);
      #pragma unroll
      for (int mt = 0; mt < 2; mt++)
        #pragma unroll
        for (int nt = 0; nt < 4; nt++)
          acc[mt][nt] = MFMA16(af[mt], bfr[nt], acc[mt][nt]);
    }

    const float* bias = (which==0) ? bq : bk;
    const float scl = (which==0) ? 0.125f*1.44269504089f : 1.0f;
    unsigned short* Outp = ws + (which==0 ? OFF_Q : OFF_K) + (size_t)b*HH*S*DD;
    #pragma unroll
    for (int mt = 0; mt < 2; mt++){
      const int o = mbase + mt*16 + lg*4;
      const float4 bb = *(const float4*)(bias + o);
      const int hd = o >> 6, db = KI(o & 63);
      #pragma unroll
      for (int nt = 0; nt < 4; nt++){
        const int p = nbase + nt*16 + lq;
        f32x4 v = acc[mt][nt];
        ushort4 r;
        r.x = f2bf((v[0]+bb.x)*scl); r.y = f2bf((v[1]+bb.y)*scl);
        r.z = f2bf((v[2]+bb.z)*scl); r.w = f2bf((v[3]+bb.w)*scl);
        *(ushort4*)(Outp + ((size_t)hd*S + p)*DD + db) = r;
      }
    }
  } else {
    const int r0 = bid - 512;
    const int b = r0 >> 7;
    const int tile = r0 & 127;
    const int mtile = tile >> 2;
    const int ntile = tile & 3;
    const int mbase = mtile*128 + (wave>>1)*64;
    const int nbase = ntile*64 + (wave&1)*32;
    const unsigned short* Amat = ws + OFF_NX + (size_t)b*S*CC;
    const unsigned short* Bmat = ws + OFF_WV;

    f32x4 acc[4][2];
    #pragma unroll
    for (int i = 0; i < 4; i++)
      #pragma unroll
      for (int j = 0; j < 2; j++)
        acc[i][j] = (f32x4){0.f,0.f,0.f,0.f};

    const unsigned short* Arow = Amat + (size_t)mbase*CC + lofs;
    const unsigned short* Brow = Bmat + (size_t)nbase*CC + lofs;
    for (int ks = 0; ks < CC; ks += 32) {
      bf16x8 af[4], bfr[2];
      #pragma unroll
      for (int mt = 0; mt < 4; mt++)
        af[mt] = *(const bf16x8*)(Arow + mt*16*CC + ks*16);
      #pragma unroll
      for (int nt = 0; nt < 2; nt++)
        bfr[nt] = *(const bf16x8*)(Brow + nt*16*CC + ks*16);
      #pragma unroll
      for (int mt = 0; mt < 4; mt++)
        #pragma unroll
        for (int nt = 0; nt < 2; nt++)
          acc[mt][nt] = MFMA16(af[mt], bfr[nt], acc[mt][nt]);
    }

    unsigned short* Outp = ws + OFF_V + (size_t)b*CC*S;
    #pragma unroll
    for (int nt = 0; nt < 2; nt++){
      const int o = nbase + nt*16 + lq;
      const float bb = bv[o];
      #pragma unroll
      for (int mt = 0; mt < 4; mt++){
        const int p = mbase + mt*16 + lg*4;
        f32x4 v = acc[mt][nt];
        ushort4 r;
        r.x = f2bf(v[0]+bb); r.y = f2bf(v[1]+bb);
        r.z = f2bf(v[2]+bb); r.w = f2bf(v[3]+bb);
        *(ushort4*)(Outp + (size_t)o*S + KI(p)) = r;
      }
    }
  }
}

// ---------------- flash attention: 3-way split-t, 3 blocks/CU, VALU diet ----------------
// R12-verbatim (runtime-cur double buffer -- the unrolled-template variant mis-schedules).
__global__ __launch_bounds__(256, 3) void attn_k(unsigned short* __restrict__ ws)
{
  __shared__ __align__(1024) char lds[32768];   // K: 0/8192, V: 16384/24576
  const int tid = threadIdx.x;
  const int lane = tid & 63, wave = tid >> 6;
  const int lq = lane & 15, lg = lane >> 4;
  const int rsw = (lq & 7) << 4;
  const int bid = blockIdx.x;
  const int bh = bid & 7;
  const int rest = bid >> 3;                // 0..95
  const int qblk = rest & 31;
  const int ch = rest >> 5;                 // 0..2
  const int tBeg = ch*1344 + (ch ? 64 : 0);
  const int tEnd = tBeg + 1344 + (ch ? 0 : 64);
  const unsigned short* Qp = ws + OFF_Q + (size_t)bh*S*DD;
  const unsigned short* Kp = ws + OFF_K + (size_t)bh*S*DD;
  const int b = bh >> 2, h = bh & 3;
  const unsigned short* Vp = ws + OFF_V + ((size_t)b*CC + h*DD)*S;
  const int qbw = qblk*128 + wave*32;

  bf16x8 qf[2][2];
  #pragma unroll
  for (int f = 0; f < 2; f++)
    #pragma unroll
    for (int hh = 0; hh < 2; hh++)
      qf[f][hh] = *(const bf16x8*)(Qp + (size_t)(qbw + f*16 + lq)*DD + hh*32 + lg*8);

  bf16x8 ones;
  #pragma unroll
  for (int i = 0; i < 8; i++) ones[i] = (__bf16)1.0f;

  const int csel = ((lane & 7) ^ ((lane >> 3) & 7)) * 8;
  const int srow = wave*16 + (lane >> 3);
  const int kofs0 = lq*128 + ((lg*16) ^ rsw);
  const int kofs1 = kofs0 ^ 64;

  f32x4 acc[4][2];
  #pragma unroll
  for (int i = 0; i < 4; i++)
    #pragma unroll
    for (int f = 0; f < 2; f++)
      acc[i][f] = (f32x4){0.f,0.f,0.f,0.f};
  f32x4 accL[2] = {(f32x4){0.f,0.f,0.f,0.f}, (f32x4){0.f,0.f,0.f,0.f}};
  float mr[2] = {-1e30f, -1e30f};

  #pragma unroll
  for (int j = 0; j < 2; j++){
    const int row = srow + j*8;
    GLOAD_LDS16(Kp + (size_t)(tBeg + row)*DD + csel, lds + wave*2048 + j*1024);
    GLOAD_LDS16(Vp + (size_t)row*S + tBeg + csel,    lds + 16384 + wave*2048 + j*1024);
  }
  __syncthreads();

  int cur = 0;
  for (int t0 = tBeg; t0 < tEnd; t0 += 64){
    const char* kb = lds + cur*8192;
    const char* vb = lds + 16384 + cur*8192;
    if (t0 + 64 < tEnd){
      char* kn = lds + (cur^1)*8192;
      char* vn = lds + 16384 + (cur^1)*8192;
      #pragma unroll
      for (int j = 0; j < 2; j++){
        const int row = srow + j*8;
        GLOAD_LDS16(Kp + (size_t)(t0 + 64 + row)*DD + csel, kn + wave*2048 + j*1024);
        GLOAD_LDS16(Vp + (size_t)row*S + (t0 + 64) + csel,  vn + wave*2048 + j*1024);
      }
    }
    bf16x8 kf[4][2];
    #pragma unroll
    for (int mt = 0; mt < 4; mt++){
      kf[mt][0] = *(const bf16x8*)(kb + mt*2048 + kofs0);
      kf[mt][1] = *(const bf16x8*)(kb + mt*2048 + kofs1);
    }
    f32x4 st[2][4];
    #pragma unroll
    for (int f = 0; f < 2; f++)
      #pragma unroll
      for (int mt = 0; mt < 4; mt++){
        f32x4 z = (f32x4){0.f,0.f,0.f,0.f};
        z = MFMA16(kf[mt][0], qf[f][0], z);
        z = MFMA16(kf[mt][1], qf[f][1], z);
        st[f][mt] = z;
      }
    bf16x8 vf[4][2];
    #pragma unroll
    for (int dt = 0; dt < 4; dt++){
      vf[dt][0] = *(const bf16x8*)(vb + dt*2048 + kofs0);
      vf[dt][1] = *(const bf16x8*)(vb + dt*2048 + kofs1);
    }
    // online softmax (exp2 domain), defer-max THR=8; max tree via v_max3
    float tmv[2];
    #pragma unroll
    for (int f = 0; f < 2; f++){
      float m1 = max3f(st[f][0][0], st[f][0][1], st[f][0][2]);
      float m2 = max3f(st[f][0][3], st[f][1][0], st[f][1][1]);
      float m3 = max3f(st[f][1][2], st[f][1][3], st[f][2][0]);
      float m4 = max3f(st[f][2][1], st[f][2][2], st[f][2][3]);
      float m5 = max3f(st[f][3][0], st[f][3][1], st[f][3][2]);
      float tm = fmaxf(fmaxf(max3f(m1, m2, m3), fmaxf(m4, m5)), st[f][3][3]);
      tm = fmaxf(tm, __shfl_xor(tm, 16));
      tm = fmaxf(tm, __shfl_xor(tm, 32));
      tmv[f] = tm;
    }
    if (!__all((tmv[0] <= mr[0] + 8.f) && (tmv[1] <= mr[1] + 8.f))){
      #pragma unroll
      for (int f = 0; f < 2; f++){
        const float mnew = fmaxf(mr[f], tmv[f]);
        const float c = __builtin_amdgcn_exp2f(mr[f] - mnew);
        #pragma unroll
        for (int dt = 0; dt < 4; dt++)
          #pragma unroll
          for (int r = 0; r < 4; r++)
            acc[dt][f][r] *= c;
        #pragma unroll
        for (int r = 0; r < 4; r++) accL[f][r] *= c;
        mr[f] = mnew;
      }
    }
    union PU { bf16x8 v; unsigned u[4]; } p0[2], p1[2];
    #pragma unroll
    for (int f = 0; f < 2; f++){
      #pragma unroll
      for (int mt = 0; mt < 4; mt++){
        float e0 = __builtin_amdgcn_exp2f(st[f][mt][0] - mr[f]);
        float e1 = __builtin_amdgcn_exp2f(st[f][mt][1] - mr[f]);
        float e2 = __builtin_amdgcn_exp2f(st[f][mt][2] - mr[f]);
        float e3 = __builtin_amdgcn_exp2f(st[f][mt][3] - mr[f]);
        if (mt < 2){ p0[f].u[mt*2] = cvtpk(e0, e1); p0[f].u[mt*2+1] = cvtpk(e2, e3); }
        else       { p1[f].u[(mt-2)*2] = cvtpk(e0, e1); p1[f].u[(mt-2)*2+1] = cvtpk(e2, e3); }
      }
    }
    // PV + l-sum (ones-A MFMA)
    #pragma unroll
    for (int dt = 0; dt < 4; dt++)
      #pragma unroll
      for (int f = 0; f < 2; f++){
        f32x4 a = acc[dt][f];
        a = MFMA16(vf[dt][0], p0[f].v, a);
        a = MFMA16(vf[dt][1], p1[f].v, a);
        acc[dt][f] = a;
      }
    #pragma unroll
    for (int f = 0; f < 2; f++){
      accL[f] = MFMA16(ones, p0[f].v, accL[f]);
      accL[f] = MFMA16(ones, p1[f].v, accL[f]);
    }
    __syncthreads();
    cur ^= 1;
  }

  // epilogue: unnormalized partials (PACC bf16) + m/l
  unsigned short* PA = pacc_base(ws, ch) + (size_t)bh*S*DD;
  float* ML = (float*)(ws + OFF_Q) + ((size_t)ch*8 + bh)*S*2;
  #pragma unroll
  for (int f = 0; f < 2; f++){
    const int q = qbw + f*16 + lq;
    #pragma unroll
    for (int dt = 0; dt < 4; dt++)
      *(ushort4*)(PA + (size_t)q*DD + dt*16 + lg*4) = pk4(acc[dt][f]);
    if (lg == 0){
      ML[(size_t)q*2]   = mr[f];
      ML[(size_t)q*2+1] = accL[f][0];
    }
  }
}

// ---------------- output projection: merge + GEMM + residual, 512 blocks (2/CU) ----------------
// ONE change vs R12: tile 32q x 128o (PACC merged 2x instead of 4x); wave = 16q x 64o.
__global__ __launch_bounds__(256, 2) void outproj_k(unsigned short* __restrict__ ws,
    const float* __restrict__ bo, const float* __restrict__ x, float* __restrict__ out)
{
  __shared__ unsigned short ldsA[8192];     // 32 x 256 blocked, 16KB
  __shared__ float wtab[32][4][3];
  const int tid = threadIdx.x;
  const int lane = tid & 63, wave = tid >> 6;
  const int lq = lane & 15, lg = lane >> 4;
  const int lofs = lq*32 + lg*8;
  const int bid = blockIdx.x;
  const int b = bid >> 8;
  const int r0 = bid & 255;
  const int mtile = r0 >> 1;                // 128 q-tiles of 32
  const int ntile = r0 & 1;                 // 2 o-halves of 128
  const int qg = mtile*32;

  // phase 1: merge weights per (q,h)
  if (tid < 128){
    const int q = tid >> 2, h = tid & 3;
    const float* MLb = (const float*)(ws + OFF_Q);
    float m[3], l[3];
    #pragma unroll
    for (int c = 0; c < 3; c++){
      const float* p = MLb + (((size_t)c*8 + b*4 + h)*S + (qg + q))*2;
      m[c] = p[0]; l[c] = p[1];
    }
    const float M = fmaxf(m[0], fmaxf(m[1], m[2]));
    const float w0 = __builtin_amdgcn_exp2f(m[0] - M);
    const float w1 = __builtin_amdgcn_exp2f(m[1] - M);
    const float w2 = __builtin_amdgcn_exp2f(m[2] - M);
    const float inv = 1.0f / (w0*l[0] + w1*l[1] + w2*l[2]);
    wtab[q][h][0] = w0*inv; wtab[q][h][1] = w1*inv; wtab[q][h][2] = w2*inv;
  }
  __syncthreads();

  // phase 2: merge 32q x 256c into blocked LDS A-tile
  #pragma unroll
  for (int it = 0; it < 8; it++){
    const int w = it*256 + tid;
    const int q = w >> 6, cq = w & 63;
    const int h = cq >> 4, d = (cq & 15)*4;
    const size_t po = ((size_t)(b*4 + h)*S + (qg + q))*DD + d;
    const ushort4 a0 = *(const ushort4*)(ws + OFF_NY + po);
    const ushort4 a1 = *(const ushort4*)(ws + OFF_NX + po);
    const ushort4 a2 = *(const ushort4*)(ws + OFF_AO + po);
    const float w0 = wtab[q][h][0], w1 = wtab[q][h][1], w2 = wtab[q][h][2];
    f32x4 v;
    v[0] = bf2f(a0.x)*w0 + bf2f(a1.x)*w1 + bf2f(a2.x)*w2;
    v[1] = bf2f(a0.y)*w0 + bf2f(a1.y)*w1 + bf2f(a2.y)*w2;
    v[2] = bf2f(a0.z)*w0 + bf2f(a1.z)*w1 + bf2f(a2.z)*w2;
    v[3] = bf2f(a0.w)*w0 + bf2f(a1.w)*w1 + bf2f(a2.w)*w2;
    *(ushort4*)(ldsA + BL256(q, cq*4)) = pk4(v);
  }
  __syncthreads();

  // phase 3: GEMM 32q x 128o (A from LDS, B=WO from global) + bias + residual
  const int mf = wave & 1;                  // 2 m-frags of 16 q
  const int nb = ntile*128 + (wave >> 1)*64;
  f32x4 acc[4];
  #pragma unroll
  for (int i = 0; i < 4; i++) acc[i] = (f32x4){0.f,0.f,0.f,0.f};
  const unsigned short* Arow = ldsA + mf*16*CC + lofs;
  const unsigned short* Brow = ws + OFF_WO + (size_t)nb*CC + lofs;
  for (int ks = 0; ks < CC; ks += 32) {
    bf16x8 af = *(const bf16x8*)(Arow + ks*16);
    bf16x8 bfr[4];
    #pragma unroll
    for (int nt = 0; nt < 4; nt++)
      bfr[nt] = *(const bf16x8*)(Brow + nt*16*CC + ks*16);
    #pragma unroll
    for (int nt = 0; nt < 4; nt++)
      acc[nt] = MFMA16(af, bfr[nt], acc[nt]);
  }
  #pragma unroll
  for (int nt = 0; nt < 4; nt++){
    const int o = nb + nt*16 + lq;
    const float bb = bo[o];
    const int p = qg + mf*16 + lg*4;
    const size_t idx = ((size_t)b*CC + o)*S + p;
    const float4 xr = *(const float4*)(x + idx);
    f32x4 v = acc[nt];
    float4 r; r.x = v[0]+bb+xr.x; r.y = v[1]+bb+xr.y; r.z = v[2]+bb+xr.z; r.w = v[3]+bb+xr.w;
    *(float4*)(out + idx) = r;
  }
}

extern "C" void kernel_launch(void* const* d_in, const int* in_sizes, int n_in,
                              void* d_out, int out_size, void* d_ws, size_t ws_size,
                              hipStream_t stream) {
  const float* x  = (const float*)d_in[0];
  const float* y  = (const float*)d_in[1];
  const float* g1 = (const float*)d_in[2];
  const float* b1 = (const float*)d_in[3];
  const float* g2 = (const float*)d_in[4];
  const float* b2 = (const float*)d_in[5];
  const float* wq = (const float*)d_in[6];
  const float* bq = (const float*)d_in[7];
  const float* wk = (const float*)d_in[8];
  const float* bk = (const float*)d_in[9];
  const float* wv = (const float*)d_in[10];
  const float* bv = (const float*)d_in[11];
  const float* wo = (const float*)d_in[12];
  const float* bo = (const float*)d_in[13];
  float* out = (float*)d_out;
  unsigned short* ws16 = (unsigned short*)d_ws;

  prep_k   <<<384, 256, 0, stream>>>(x, y, g1, b1, g2, b2, wq, wk, wv, wo, ws16);
  qkv_gemm <<<768, 256, 0, stream>>>(ws16, bq, bk, bv);
  attn_k   <<<768, 256, 0, stream>>>(ws16);
  outproj_k<<<512, 256, 0, stream>>>(ws16, bo, x, out);
}

// Round 15
// 104.807 us; speedup vs baseline: 1.8602x; 1.0081x over previous
//
#include <hip/hip_runtime.h>

typedef __bf16 bf16_t;
typedef bf16_t bf16x8 __attribute__((ext_vector_type(8)));
typedef float f32x4 __attribute__((ext_vector_type(4)));

#define MFMA16(a,b,c) __builtin_amdgcn_mfma_f32_16x16x32_bf16((a),(b),(c),0,0,0)

#define GLOAD_LDS16(gsrc, ldst) \
  __builtin_amdgcn_global_load_lds((const __attribute__((address_space(1))) unsigned int*)(gsrc), \
                                   (__attribute__((address_space(3))) unsigned int*)(ldst), 16, 0, 0)

__device__ __forceinline__ unsigned short f2bf(float f){
  unsigned int u = __builtin_bit_cast(unsigned int, f);
  u = (u + 0x7FFFu + ((u >> 16) & 1u)) >> 16;
  return (unsigned short)u;
}
__device__ __forceinline__ float bf2f(unsigned short u){
  return __builtin_bit_cast(float, (unsigned int)u << 16);
}
__device__ __forceinline__ ushort4 pk4(f32x4 v){
  union { __bf16 b[4]; ushort4 u; } r;
  r.b[0]=(__bf16)v[0]; r.b[1]=(__bf16)v[1]; r.b[2]=(__bf16)v[2]; r.b[3]=(__bf16)v[3];
  return r.u;
}
__device__ __forceinline__ unsigned cvtpk(float lo, float hi){
  unsigned r; asm("v_cvt_pk_bf16_f32 %0, %1, %2" : "=v"(r) : "v"(lo), "v"(hi)); return r;
}
__device__ __forceinline__ float max3f(float a, float b, float c){
  float r; asm("v_max3_f32 %0, %1, %2, %3" : "=v"(r) : "v"(a), "v"(b), "v"(c)); return r;
}

// KI: k-interleave within 64-elem segment (for Q/K/V consumed by attention).
__device__ __forceinline__ int KI(int d){   // d 4-aligned
  int gi = (d >> 2) & 15;
  int pos = (gi & 8) | ((gi & 3) << 1) | ((gi >> 2) & 1);
  return (d & ~63) | (pos << 2);
}

// Blocked fragment layout for GEMM operands [R][256]:
// wave fragment load at (rowbase*256 + ks*16 + lq*32 + lg*8) is contiguous 1KB.
__device__ __forceinline__ int BL256(int r, int c){
  return ((r >> 4) << 12) + (((c >> 5)) << 9) + ((r & 15) << 5)
       + (((c & 15) >> 2) << 3) + (((c >> 4) & 1) << 2) + (c & 3);
}

constexpr int BN = 2;
constexpr int CC = 256;
constexpr int S  = 4096;
constexpr int HH = 4;
constexpr int DD = 64;

constexpr size_t OFF_WQ = 0;
constexpr size_t OFF_WK = 65536;
constexpr size_t OFF_WV = 131072;
constexpr size_t OFF_WO = 196608;
constexpr size_t OFF_NY = 262144;                      // blocked [p][c]
constexpr size_t OFF_NX = OFF_NY + (size_t)BN*S*CC;    // blocked [p][c]
constexpr size_t OFF_Q  = OFF_NX + (size_t)BN*S*CC;    // [b][h][p][d~KI] (pre-scaled 0.125*log2e)
constexpr size_t OFF_K  = OFF_Q  + (size_t)BN*S*CC;    // [b][h][p][d~KI]
constexpr size_t OFF_V  = OFF_K  + (size_t)BN*S*CC;    // [b][c][p~KI]
constexpr size_t OFF_AO = OFF_V  + (size_t)BN*S*CC;    // (dead after qkv: reused as PACC ch2)
// Attention partials (3 t-chunks): ch0->NY, ch1->NX, ch2->AO (dead after qkv_gemm).
// ML [3][8][4096][2] f32 overlays OFF_Q (clobbers Q[bh0..1.5]). SAFE: attn grid (768)
// is fully co-resident (3 blocks/CU via __launch_bounds__(256,3)); every block reads Q
// in its prologue long before any epilogue ML write. qkv rewrites Q each call.
__device__ __forceinline__ unsigned short* pacc_base(unsigned short* ws, int ch){
  return ws + (ch == 0 ? OFF_NY : (ch == 1 ? OFF_NX : OFF_AO));
}

// ---------------- fused weight-convert + GroupNorm ----------------
__global__ __launch_bounds__(256) void prep_k(const float* __restrict__ x, const float* __restrict__ y,
    const float* __restrict__ g1, const float* __restrict__ b1,
    const float* __restrict__ g2, const float* __restrict__ b2,
    const float* __restrict__ wq, const float* __restrict__ wk,
    const float* __restrict__ wv, const float* __restrict__ wo,
    unsigned short* __restrict__ ws)
{
  __shared__ float red[8];
  __shared__ float mv[2];
  const int tid = threadIdx.x;
  const int bid = blockIdx.x;

  if (bid >= 128){
    const int idx = (bid - 128)*256 + tid;
    const int m = idx >> 14;
    const int off = (idx & 16383) << 2;
    const float* src = (m==0) ? wq : (m==1) ? wk : (m==2) ? wv : wo;
    float4 v = *(const float4*)(src + off);
    ushort4 r; r.x=f2bf(v.x); r.y=f2bf(v.y); r.z=f2bf(v.z); r.w=f2bf(v.w);
    const int o = off >> 8, c = off & 255;
    *(ushort4*)(ws + (size_t)m*65536 + BL256(o, c)) = r;
    return;
  }

  const int tsel = bid >> 6;
  const int rem  = bid & 63;
  const int b = rem >> 5, g = rem & 31;
  const float* in = (tsel ? y : x) + ((size_t)b*CC + g*8)*S;
  unsigned short* outp = ws + (tsel ? OFF_NY : OFF_NX) + (size_t)b*S*CC;
  const int j = g & 3;
  const int gk = (g >> 2) * 512;
  const int posA = (j & 1)*16 + (j >> 1)*4;
  const int posB = posA + 8;
  const float* gamma = (tsel ? g2 : g1) + g*8;
  const float* beta  = (tsel ? b2 : b1) + g*8;

  float s = 0.f, ss = 0.f;
  #pragma unroll
  for (int ci = 0; ci < 8; ci++){
    const float4* row = (const float4*)(in + (size_t)ci*S);
    #pragma unroll
    for (int i = 0; i < 4; i++){
      float4 v = row[tid + i*256];
      s  += v.x + v.y + v.z + v.w;
      ss += v.x*v.x + v.y*v.y + v.z*v.z + v.w*v.w;
    }
  }
  #pragma unroll
  for (int off = 1; off < 64; off <<= 1){
    s  += __shfl_xor(s,  off);
    ss += __shfl_xor(ss, off);
  }
  const int wave = tid >> 6, lane = tid & 63;
  if (lane == 0){ red[wave] = s; red[4+wave] = ss; }
  __syncthreads();
  if (tid == 0){
    float S1 = red[0]+red[1]+red[2]+red[3];
    float S2 = red[4]+red[5]+red[6]+red[7];
    const float invn = 1.0f/32768.0f;
    float mean = S1*invn;
    float var  = S2*invn - mean*mean;
    mv[0] = mean; mv[1] = rsqrtf(var + 1e-6f);
  }
  __syncthreads();
  const float mean = mv[0], rstd = mv[1];
  float sc[8], sh[8];
  #pragma unroll
  for (int ci = 0; ci < 8; ci++){ sc[ci] = rstd*gamma[ci]; sh[ci] = beta[ci] - mean*sc[ci]; }
  for (int i = 0; i < 16; i++){
    const int p = tid + i*256;
    const int base = ((p >> 4) << 12) + gk + ((p & 15) << 5);
    ushort4 a0, a1;
    a0.x = f2bf(in[0*S+p]*sc[0]+sh[0]);
    a0.y = f2bf(in[1*S+p]*sc[1]+sh[1]);
    a0.z = f2bf(in[2*S+p]*sc[2]+sh[2]);
    a0.w = f2bf(in[3*S+p]*sc[3]+sh[3]);
    a1.x = f2bf(in[4*S+p]*sc[4]+sh[4]);
    a1.y = f2bf(in[5*S+p]*sc[5]+sh[5]);
    a1.z = f2bf(in[6*S+p]*sc[6]+sh[6]);
    a1.w = f2bf(in[7*S+p]*sc[7]+sh[7]);
    *(ushort4*)(outp + base + posA) = a0;
    *(ushort4*)(outp + base + posB) = a1;
  }
}

// ---------------- Q/K/V projection GEMMs, 768 blocks (3/CU) ----------------
// R15 change: epilogues stage results in a 16KB XOR-swizzled LDS tile, then write
// global memory fully coalesced (16B/lane contiguous chunks). Values identical.
__global__ __launch_bounds__(256, 3) void qkv_gemm(unsigned short* __restrict__ ws,
    const float* __restrict__ bq, const float* __restrict__ bk, const float* __restrict__ bv)
{
  __shared__ unsigned short stg[8192];      // 16 KB epilogue staging
  const int tid = threadIdx.x;
  const int lane = tid & 63, wave = tid >> 6;
  const int lq = lane & 15, lg = lane >> 4;
  const int lofs = lq*32 + lg*8;
  const int bid = blockIdx.x;

  if (bid < 512){
    const int inst2 = bid >> 7;             // 0..3
    const int which = inst2 >> 1;           // 0=Q,1=K
    const int b = inst2 & 1;
    const int tile = bid & 127;
    const int mtile = tile & 3;             // == hd (64-aligned o-tile)
    const int ntile = tile >> 2;
    const int mbase = mtile*64 + (wave>>1)*32;
    const int nbase = ntile*128 + (wave&1)*64;
    const unsigned short* Amat = ws + (which==0 ? OFF_WQ : OFF_WK);
    const unsigned short* Bmat = ws + (which==0 ? OFF_NY : OFF_NX) + (size_t)b*S*CC;

    f32x4 acc[2][4];
    #pragma unroll
    for (int i = 0; i < 2; i++)
      #pragma unroll
      for (int j = 0; j < 4; j++)
        acc[i][j] = (f32x4){0.f,0.f,0.f,0.f};

    const unsigned short* Arow = Amat + (size_t)mbase*CC + lofs;
    const unsigned short* Brow = Bmat + (size_t)nbase*CC + lofs;
    for (int ks = 0; ks < CC; ks += 32) {
      bf16x8 af[2], bfr[4];
      #pragma unroll
      for (int mt = 0; mt < 2; mt++)
        af[mt] = *(const bf16x8*)(Arow + mt*16*CC + ks*16);
      #pragma unroll
      for (int nt = 0; nt < 4; nt++)
        bfr[nt] = *(const bf16x8*)(Brow + nt*16*CC + ks*16);
      #pragma unroll
      for (int mt = 0; mt < 2; mt++)
        #pragma unroll
        for (int nt = 0; nt < 4; nt++)
          acc[mt][nt] = MFMA16(af[mt], bfr[nt], acc[mt][nt]);
    }

    const float* bias = (which==0) ? bq : bk;
    const float scl = (which==0) ? 0.125f*1.44269504089f : 1.0f;
    unsigned short* Outp = ws + (which==0 ? OFF_Q : OFF_K) + (size_t)b*HH*S*DD;
    // stage: LDS[lp][db^swz], lp = local p (0..127), db = KI(local o)
    #pragma unroll
    for (int mt = 0; mt < 2; mt++){
      const int o = mbase + mt*16 + lg*4;
      const float4 bb = *(const float4*)(bias + o);
      const int db = KI(o & 63);
      #pragma unroll
      for (int nt = 0; nt < 4; nt++){
        const int lp = (wave&1)*64 + nt*16 + lq;
        f32x4 v = acc[mt][nt];
        ushort4 r;
        r.x = f2bf((v[0]+bb.x)*scl); r.y = f2bf((v[1]+bb.y)*scl);
        r.z = f2bf((v[2]+bb.z)*scl); r.w = f2bf((v[3]+bb.w)*scl);
        *(ushort4*)(stg + lp*64 + (db ^ ((lp & 7) << 3))) = r;
      }
    }
    __syncthreads();
    // write out: 128 rows x 64 elems (128B/row), fully coalesced
    #pragma unroll
    for (int k = 0; k < 4; k++){
      const int c = tid + k*256;
      const int row = c >> 3, gl = (c & 7) << 3;
      uint4 v = *(const uint4*)(stg + row*64 + (gl ^ ((row & 7) << 3)));
      *(uint4*)(Outp + ((size_t)mtile*S + ntile*128 + row)*DD + gl) = v;
    }
  } else {
    const int r0 = bid - 512;
    const int b = r0 >> 7;
    const int tile = r0 & 127;
    const int mtile = tile >> 2;
    const int ntile = tile & 3;
    const int mbase = mtile*128 + (wave>>1)*64;
    const int nbase = ntile*64 + (wave&1)*32;
    const unsigned short* Amat = ws + OFF_NX + (size_t)b*S*CC;
    const unsigned short* Bmat = ws + OFF_WV;

    f32x4 acc[4][2];
    #pragma unroll
    for (int i = 0; i < 4; i++)
      #pragma unroll
      for (int j = 0; j < 2; j++)
        acc[i][j] = (f32x4){0.f,0.f,0.f,0.f};

    const unsigned short* Arow = Amat + (size_t)mbase*CC + lofs;
    const unsigned short* Brow = Bmat + (size_t)nbase*CC + lofs;
    for (int ks = 0; ks < CC; ks += 32) {
      bf16x8 af[4], bfr[2];
      #pragma unroll
      for (int mt = 0; mt < 4; mt++)
        af[mt] = *(const bf16x8*)(Arow + mt*16*CC + ks*16);
      #pragma unroll
      for (int nt = 0; nt < 2; nt++)
        bfr[nt] = *(const bf16x8*)(Brow + nt*16*CC + ks*16);
      #pragma unroll
      for (int mt = 0; mt < 4; mt++)
        #pragma unroll
        for (int nt = 0; nt < 2; nt++)
          acc[mt][nt] = MFMA16(af[mt], bfr[nt], acc[mt][nt]);
    }

    unsigned short* Outp = ws + OFF_V + (size_t)b*CC*S;
    // stage: LDS[ro][KI(lp)^swz], ro = local o (0..63), lp = local p (0..127)
    #pragma unroll
    for (int nt = 0; nt < 2; nt++){
      const int o = nbase + nt*16 + lq;
      const int ro = o - ntile*64;
      const float bb = bv[o];
      #pragma unroll
      for (int mt = 0; mt < 4; mt++){
        const int lp = (wave>>1)*64 + mt*16 + lg*4;
        f32x4 v = acc[mt][nt];
        ushort4 r;
        r.x = f2bf(v[0]+bb); r.y = f2bf(v[1]+bb);
        r.z = f2bf(v[2]+bb); r.w = f2bf(v[3]+bb);
        *(ushort4*)(stg + ro*128 + (KI(lp) ^ ((ro & 7) << 3))) = r;
      }
    }
    __syncthreads();
    // write out: 64 rows(o) x 128 elems (256B/row), coalesced segments
    #pragma unroll
    for (int k = 0; k < 4; k++){
      const int c = tid + k*256;
      const int row = c >> 4, gl = (c & 15) << 3;
      uint4 v = *(const uint4*)(stg + row*128 + (gl ^ ((row & 7) << 3)));
      *(uint4*)(Outp + (size_t)(ntile*64 + row)*S + mtile*128 + gl) = v;
    }
  }
}

// ---------------- flash attention: 3-way split-t, 3 blocks/CU, VALU diet ----------------
// R12/R14-verbatim (runtime-cur double buffer -- the unrolled-template variant mis-schedules).
__global__ __launch_bounds__(256, 3) void attn_k(unsigned short* __restrict__ ws)
{
  __shared__ __align__(1024) char lds[32768];   // K: 0/8192, V: 16384/24576
  const int tid = threadIdx.x;
  const int lane = tid & 63, wave = tid >> 6;
  const int lq = lane & 15, lg = lane >> 4;
  const int rsw = (lq & 7) << 4;
  const int bid = blockIdx.x;
  const int bh = bid & 7;
  const int rest = bid >> 3;                // 0..95
  const int qblk = rest & 31;
  const int ch = rest >> 5;                 // 0..2
  const int tBeg = ch*1344 + (ch ? 64 : 0);
  const int tEnd = tBeg + 1344 + (ch ? 0 : 64);
  const unsigned short* Qp = ws + OFF_Q + (size_t)bh*S*DD;
  const unsigned short* Kp = ws + OFF_K + (size_t)bh*S*DD;
  const int b = bh >> 2, h = bh & 3;
  const unsigned short* Vp = ws + OFF_V + ((size_t)b*CC + h*DD)*S;
  const int qbw = qblk*128 + wave*32;

  bf16x8 qf[2][2];
  #pragma unroll
  for (int f = 0; f < 2; f++)
    #pragma unroll
    for (int hh = 0; hh < 2; hh++)
      qf[f][hh] = *(const bf16x8*)(Qp + (size_t)(qbw + f*16 + lq)*DD + hh*32 + lg*8);

  bf16x8 ones;
  #pragma unroll
  for (int i = 0; i < 8; i++) ones[i] = (__bf16)1.0f;

  const int csel = ((lane & 7) ^ ((lane >> 3) & 7)) * 8;
  const int srow = wave*16 + (lane >> 3);
  const int kofs0 = lq*128 + ((lg*16) ^ rsw);
  const int kofs1 = kofs0 ^ 64;

  f32x4 acc[4][2];
  #pragma unroll
  for (int i = 0; i < 4; i++)
    #pragma unroll
    for (int f = 0; f < 2; f++)
      acc[i][f] = (f32x4){0.f,0.f,0.f,0.f};
  f32x4 accL[2] = {(f32x4){0.f,0.f,0.f,0.f}, (f32x4){0.f,0.f,0.f,0.f}};
  float mr[2] = {-1e30f, -1e30f};

  #pragma unroll
  for (int j = 0; j < 2; j++){
    const int row = srow + j*8;
    GLOAD_LDS16(Kp + (size_t)(tBeg + row)*DD + csel, lds + wave*2048 + j*1024);
    GLOAD_LDS16(Vp + (size_t)row*S + tBeg + csel,    lds + 16384 + wave*2048 + j*1024);
  }
  __syncthreads();

  int cur = 0;
  for (int t0 = tBeg; t0 < tEnd; t0 += 64){
    const char* kb = lds + cur*8192;
    const char* vb = lds + 16384 + cur*8192;
    if (t0 + 64 < tEnd){
      char* kn = lds + (cur^1)*8192;
      char* vn = lds + 16384 + (cur^1)*8192;
      #pragma unroll
      for (int j = 0; j < 2; j++){
        const int row = srow + j*8;
        GLOAD_LDS16(Kp + (size_t)(t0 + 64 + row)*DD + csel, kn + wave*2048 + j*1024);
        GLOAD_LDS16(Vp + (size_t)row*S + (t0 + 64) + csel,  vn + wave*2048 + j*1024);
      }
    }
    bf16x8 kf[4][2];
    #pragma unroll
    for (int mt = 0; mt < 4; mt++){
      kf[mt][0] = *(const bf16x8*)(kb + mt*2048 + kofs0);
      kf[mt][1] = *(const bf16x8*)(kb + mt*2048 + kofs1);
    }
    f32x4 st[2][4];
    #pragma unroll
    for (int f = 0; f < 2; f++)
      #pragma unroll
      for (int mt = 0; mt < 4; mt++){
        f32x4 z = (f32x4){0.f,0.f,0.f,0.f};
        z = MFMA16(kf[mt][0], qf[f][0], z);
        z = MFMA16(kf[mt][1], qf[f][1], z);
        st[f][mt] = z;
      }
    bf16x8 vf[4][2];
    #pragma unroll
    for (int dt = 0; dt < 4; dt++){
      vf[dt][0] = *(const bf16x8*)(vb + dt*2048 + kofs0);
      vf[dt][1] = *(const bf16x8*)(vb + dt*2048 + kofs1);
    }
    // online softmax (exp2 domain), defer-max THR=8; max tree via v_max3
    float tmv[2];
    #pragma unroll
    for (int f = 0; f < 2; f++){
      float m1 = max3f(st[f][0][0], st[f][0][1], st[f][0][2]);
      float m2 = max3f(st[f][0][3], st[f][1][0], st[f][1][1]);
      float m3 = max3f(st[f][1][2], st[f][1][3], st[f][2][0]);
      float m4 = max3f(st[f][2][1], st[f][2][2], st[f][2][3]);
      float m5 = max3f(st[f][3][0], st[f][3][1], st[f][3][2]);
      float tm = fmaxf(fmaxf(max3f(m1, m2, m3), fmaxf(m4, m5)), st[f][3][3]);
      tm = fmaxf(tm, __shfl_xor(tm, 16));
      tm = fmaxf(tm, __shfl_xor(tm, 32));
      tmv[f] = tm;
    }
    if (!__all((tmv[0] <= mr[0] + 8.f) && (tmv[1] <= mr[1] + 8.f))){
      #pragma unroll
      for (int f = 0; f < 2; f++){
        const float mnew = fmaxf(mr[f], tmv[f]);
        const float c = __builtin_amdgcn_exp2f(mr[f] - mnew);
        #pragma unroll
        for (int dt = 0; dt < 4; dt++)
          #pragma unroll
          for (int r = 0; r < 4; r++)
            acc[dt][f][r] *= c;
        #pragma unroll
        for (int r = 0; r < 4; r++) accL[f][r] *= c;
        mr[f] = mnew;
      }
    }
    union PU { bf16x8 v; unsigned u[4]; } p0[2], p1[2];
    #pragma unroll
    for (int f = 0; f < 2; f++){
      #pragma unroll
      for (int mt = 0; mt < 4; mt++){
        float e0 = __builtin_amdgcn_exp2f(st[f][mt][0] - mr[f]);
        float e1 = __builtin_amdgcn_exp2f(st[f][mt][1] - mr[f]);
        float e2 = __builtin_amdgcn_exp2f(st[f][mt][2] - mr[f]);
        float e3 = __builtin_amdgcn_exp2f(st[f][mt][3] - mr[f]);
        if (mt < 2){ p0[f].u[mt*2] = cvtpk(e0, e1); p0[f].u[mt*2+1] = cvtpk(e2, e3); }
        else       { p1[f].u[(mt-2)*2] = cvtpk(e0, e1); p1[f].u[(mt-2)*2+1] = cvtpk(e2, e3); }
      }
    }
    // PV + l-sum (ones-A MFMA)
    #pragma unroll
    for (int dt = 0; dt < 4; dt++)
      #pragma unroll
      for (int f = 0; f < 2; f++){
        f32x4 a = acc[dt][f];
        a = MFMA16(vf[dt][0], p0[f].v, a);
        a = MFMA16(vf[dt][1], p1[f].v, a);
        acc[dt][f] = a;
      }
    #pragma unroll
    for (int f = 0; f < 2; f++){
      accL[f] = MFMA16(ones, p0[f].v, accL[f]);
      accL[f] = MFMA16(ones, p1[f].v, accL[f]);
    }
    __syncthreads();
    cur ^= 1;
  }

  // epilogue: unnormalized partials (PACC bf16) + m/l
  unsigned short* PA = pacc_base(ws, ch) + (size_t)bh*S*DD;
  float* ML = (float*)(ws + OFF_Q) + ((size_t)ch*8 + bh)*S*2;
  #pragma unroll
  for (int f = 0; f < 2; f++){
    const int q = qbw + f*16 + lq;
    #pragma unroll
    for (int dt = 0; dt < 4; dt++)
      *(ushort4*)(PA + (size_t)q*DD + dt*16 + lg*4) = pk4(acc[dt][f]);
    if (lg == 0){
      ML[(size_t)q*2]   = mr[f];
      ML[(size_t)q*2+1] = accL[f][0];
    }
  }
}

// ---------------- output projection: merge + GEMM + residual, 512 blocks (2/CU) ----------------
// tile 32q x 128o (PACC merged 2x); wave = 16q x 64o. R14-verbatim.
__global__ __launch_bounds__(256, 2) void outproj_k(unsigned short* __restrict__ ws,
    const float* __restrict__ bo, const float* __restrict__ x, float* __restrict__ out)
{
  __shared__ unsigned short ldsA[8192];     // 32 x 256 blocked, 16KB
  __shared__ float wtab[32][4][3];
  const int tid = threadIdx.x;
  const int lane = tid & 63, wave = tid >> 6;
  const int lq = lane & 15, lg = lane >> 4;
  const int lofs = lq*32 + lg*8;
  const int bid = blockIdx.x;
  const int b = bid >> 8;
  const int r0 = bid & 255;
  const int mtile = r0 >> 1;                // 128 q-tiles of 32
  const int ntile = r0 & 1;                 // 2 o-halves of 128
  const int qg = mtile*32;

  // phase 1: merge weights per (q,h)
  if (tid < 128){
    const int q = tid >> 2, h = tid & 3;
    const float* MLb = (const float*)(ws + OFF_Q);
    float m[3], l[3];
    #pragma unroll
    for (int c = 0; c < 3; c++){
      const float* p = MLb + (((size_t)c*8 + b*4 + h)*S + (qg + q))*2;
      m[c] = p[0]; l[c] = p[1];
    }
    const float M = fmaxf(m[0], fmaxf(m[1], m[2]));
    const float w0 = __builtin_amdgcn_exp2f(m[0] - M);
    const float w1 = __builtin_amdgcn_exp2f(m[1] - M);
    const float w2 = __builtin_amdgcn_exp2f(m[2] - M);
    const float inv = 1.0f / (w0*l[0] + w1*l[1] + w2*l[2]);
    wtab[q][h][0] = w0*inv; wtab[q][h][1] = w1*inv; wtab[q][h][2] = w2*inv;
  }
  __syncthreads();

  // phase 2: merge 32q x 256c into blocked LDS A-tile
  #pragma unroll
  for (int it = 0; it < 8; it++){
    const int w = it*256 + tid;
    const int q = w >> 6, cq = w & 63;
    const int h = cq >> 4, d = (cq & 15)*4;
    const size_t po = ((size_t)(b*4 + h)*S + (qg + q))*DD + d;
    const ushort4 a0 = *(const ushort4*)(ws + OFF_NY + po);
    const ushort4 a1 = *(const ushort4*)(ws + OFF_NX + po);
    const ushort4 a2 = *(const ushort4*)(ws + OFF_AO + po);
    const float w0 = wtab[q][h][0], w1 = wtab[q][h][1], w2 = wtab[q][h][2];
    f32x4 v;
    v[0] = bf2f(a0.x)*w0 + bf2f(a1.x)*w1 + bf2f(a2.x)*w2;
    v[1] = bf2f(a0.y)*w0 + bf2f(a1.y)*w1 + bf2f(a2.y)*w2;
    v[2] = bf2f(a0.z)*w0 + bf2f(a1.z)*w1 + bf2f(a2.z)*w2;
    v[3] = bf2f(a0.w)*w0 + bf2f(a1.w)*w1 + bf2f(a2.w)*w2;
    *(ushort4*)(ldsA + BL256(q, cq*4)) = pk4(v);
  }
  __syncthreads();

  // phase 3: GEMM 32q x 128o (A from LDS, B=WO from global) + bias + residual
  const int mf = wave & 1;                  // 2 m-frags of 16 q
  const int nb = ntile*128 + (wave >> 1)*64;
  f32x4 acc[4];
  #pragma unroll
  for (int i = 0; i < 4; i++) acc[i] = (f32x4){0.f,0.f,0.f,0.f};
  const unsigned short* Arow = ldsA + mf*16*CC + lofs;
  const unsigned short* Brow = ws + OFF_WO + (size_t)nb*CC + lofs;
  for (int ks = 0; ks < CC; ks += 32) {
    bf16x8 af = *(const bf16x8*)(Arow + ks*16);
    bf16x8 bfr[4];
    #pragma unroll
    for (int nt = 0; nt < 4; nt++)
      bfr[nt] = *(const bf16x8*)(Brow + nt*16*CC + ks*16);
    #pragma unroll
    for (int nt = 0; nt < 4; nt++)
      acc[nt] = MFMA16(af, bfr[nt], acc[nt]);
  }
  #pragma unroll
  for (int nt = 0; nt < 4; nt++){
    const int o = nb + nt*16 + lq;
    const float bb = bo[o];
    const int p = qg + mf*16 + lg*4;
    const size_t idx = ((size_t)b*CC + o)*S + p;
    const float4 xr = *(const float4*)(x + idx);
    f32x4 v = acc[nt];
    float4 r; r.x = v[0]+bb+xr.x; r.y = v[1]+bb+xr.y; r.z = v[2]+bb+xr.z; r.w = v[3]+bb+xr.w;
    *(float4*)(out + idx) = r;
  }
}

extern "C" void kernel_launch(void* const* d_in, const int* in_sizes, int n_in,
                              void* d_out, int out_size, void* d_ws, size_t ws_size,
                              hipStream_t stream) {
  const float* x  = (const float*)d_in[0];
  const float* y  = (const float*)d_in[1];
  const float* g1 = (const float*)d_in[2];
  const float* b1 = (const float*)d_in[3];
  const float* g2 = (const float*)d_in[4];
  const float* b2 = (const float*)d_in[5];
  const float* wq = (const float*)d_in[6];
  const float* bq = (const float*)d_in[7];
  const float* wk = (const float*)d_in[8];
  const float* bk = (const float*)d_in[9];
  const float* wv = (const float*)d_in[10];
  const float* bv = (const float*)d_in[11];
  const float* wo = (const float*)d_in[12];
  const float* bo = (const float*)d_in[13];
  float* out = (float*)d_out;
  unsigned short* ws16 = (unsigned short*)d_ws;

  prep_k   <<<384, 256, 0, stream>>>(x, y, g1, b1, g2, b2, wq, wk, wv, wo, ws16);
  qkv_gemm <<<768, 256, 0, stream>>>(ws16, bq, bk, bv);
  attn_k   <<<768, 256, 0, stream>>>(ws16);
  outproj_k<<<512, 256, 0, stream>>>(ws16, bo, x, out);
}

// Round 16
// 88.846 us; speedup vs baseline: 2.1944x; 1.1797x over previous
//
#include <hip/hip_runtime.h>

typedef __bf16 bf16_t;
typedef bf16_t bf16x8 __attribute__((ext_vector_type(8)));
typedef float f32x4 __attribute__((ext_vector_type(4)));

#define MFMA16(a,b,c) __builtin_amdgcn_mfma_f32_16x16x32_bf16((a),(b),(c),0,0,0)

#define GLOAD_LDS16(gsrc, ldst) \
  __builtin_amdgcn_global_load_lds((const __attribute__((address_space(1))) unsigned int*)(gsrc), \
                                   (__attribute__((address_space(3))) unsigned int*)(ldst), 16, 0, 0)

__device__ __forceinline__ unsigned short f2bf(float f){
  unsigned int u = __builtin_bit_cast(unsigned int, f);
  u = (u + 0x7FFFu + ((u >> 16) & 1u)) >> 16;
  return (unsigned short)u;
}
__device__ __forceinline__ float bf2f(unsigned short u){
  return __builtin_bit_cast(float, (unsigned int)u << 16);
}
__device__ __forceinline__ ushort4 pk4(f32x4 v){
  union { __bf16 b[4]; ushort4 u; } r;
  r.b[0]=(__bf16)v[0]; r.b[1]=(__bf16)v[1]; r.b[2]=(__bf16)v[2]; r.b[3]=(__bf16)v[3];
  return r.u;
}
__device__ __forceinline__ unsigned cvtpk(float lo, float hi){
  unsigned r; asm("v_cvt_pk_bf16_f32 %0, %1, %2" : "=v"(r) : "v"(lo), "v"(hi)); return r;
}
__device__ __forceinline__ float max3f(float a, float b, float c){
  float r; asm("v_max3_f32 %0, %1, %2, %3" : "=v"(r) : "v"(a), "v"(b), "v"(c)); return r;
}

// KI: k-interleave within 64-elem segment (for Q/K/V consumed by attention).
__device__ __forceinline__ int KI(int d){   // d 4-aligned
  int gi = (d >> 2) & 15;
  int pos = (gi & 8) | ((gi & 3) << 1) | ((gi >> 2) & 1);
  return (d & ~63) | (pos << 2);
}

// Blocked fragment layout for GEMM operands [R][256]:
// wave fragment load at (rowbase*256 + ks*16 + lq*32 + lg*8) is contiguous 1KB.
__device__ __forceinline__ int BL256(int r, int c){
  return ((r >> 4) << 12) + (((c >> 5)) << 9) + ((r & 15) << 5)
       + (((c & 15) >> 2) << 3) + (((c >> 4) & 1) << 2) + (c & 3);
}

constexpr int BN = 2;
constexpr int CC = 256;
constexpr int S  = 4096;
constexpr int HH = 4;
constexpr int DD = 64;

constexpr size_t OFF_WQ = 0;
constexpr size_t OFF_WK = 65536;
constexpr size_t OFF_WV = 131072;
constexpr size_t OFF_WO = 196608;
constexpr size_t OFF_NY = 262144;                      // blocked [p][c]
constexpr size_t OFF_NX = OFF_NY + (size_t)BN*S*CC;    // blocked [p][c]
constexpr size_t OFF_Q  = OFF_NX + (size_t)BN*S*CC;    // [b][h][p][d~KI] (pre-scaled 0.125*log2e)
constexpr size_t OFF_K  = OFF_Q  + (size_t)BN*S*CC;    // [b][h][p][d~KI]
constexpr size_t OFF_V  = OFF_K  + (size_t)BN*S*CC;    // [b][c][p~KI]
constexpr size_t OFF_AO = OFF_V  + (size_t)BN*S*CC;    // (dead after qkv: reused as PACC ch2)
// GroupNorm partial stats scratch: 256 x (s,ss) f32 at start of AO region (dead until attn).
// Attention partials (3 t-chunks): ch0->NY, ch1->NX, ch2->AO (dead after qkv_gemm).
// ML [3][8][4096][2] f32 overlays OFF_Q (clobbers Q[bh0..1.5]). SAFE: attn grid (768)
// is fully co-resident (3 blocks/CU via __launch_bounds__(256,3)); every block reads Q
// in its prologue long before any epilogue ML write. qkv rewrites Q each call.
__device__ __forceinline__ unsigned short* pacc_base(unsigned short* ws, int ch){
  return ws + (ch == 0 ? OFF_NY : (ch == 1 ? OFF_NX : OFF_AO));
}

// ---------------- GroupNorm partial stats: 256 blocks (1/CU) ----------------
// bid = tsel*128 + b*64 + g*2 + hh. Partial sums over 8ch x 2048px (half a unit).
__global__ __launch_bounds__(256) void stats_k(const float* __restrict__ x, const float* __restrict__ y,
    unsigned short* __restrict__ ws)
{
  __shared__ float red[8];
  const int tid = threadIdx.x;
  const int bid = blockIdx.x;
  const int hh = bid & 1;
  const int g = (bid >> 1) & 31;
  const int b = (bid >> 6) & 1;
  const int tsel = bid >> 7;
  const float* in = (tsel ? y : x) + ((size_t)b*CC + g*8)*S + hh*2048;

  float s = 0.f, ss = 0.f;
  #pragma unroll
  for (int ci = 0; ci < 8; ci++){
    const float4* row = (const float4*)(in + (size_t)ci*S);
    #pragma unroll
    for (int i = 0; i < 2; i++){
      float4 v = row[tid + i*256];
      s  += v.x + v.y + v.z + v.w;
      ss += v.x*v.x + v.y*v.y + v.z*v.z + v.w*v.w;
    }
  }
  #pragma unroll
  for (int off = 1; off < 64; off <<= 1){
    s  += __shfl_xor(s,  off);
    ss += __shfl_xor(ss, off);
  }
  const int wave = tid >> 6, lane = tid & 63;
  if (lane == 0){ red[wave] = s; red[4+wave] = ss; }
  __syncthreads();
  if (tid == 0){
    float* stats = (float*)(ws + OFF_AO);
    const int unit = (tsel*2 + b)*32 + g;
    stats[unit*4 + hh*2]     = red[0]+red[1]+red[2]+red[3];
    stats[unit*4 + hh*2 + 1] = red[4]+red[5]+red[6]+red[7];
  }
}

// ---------------- GroupNorm apply (vectorized) + weight convert: 512 blocks (2/CU) ----------------
__global__ __launch_bounds__(256) void apply_k(const float* __restrict__ x, const float* __restrict__ y,
    const float* __restrict__ g1, const float* __restrict__ b1,
    const float* __restrict__ g2, const float* __restrict__ b2,
    const float* __restrict__ wq, const float* __restrict__ wk,
    const float* __restrict__ wv, const float* __restrict__ wo,
    unsigned short* __restrict__ ws)
{
  const int tid = threadIdx.x;
  const int bid = blockIdx.x;

  if (bid >= 256){
    const int idx = (bid - 256)*256 + tid;
    const int m = idx >> 14;
    const int off = (idx & 16383) << 2;
    const float* src = (m==0) ? wq : (m==1) ? wk : (m==2) ? wv : wo;
    float4 v = *(const float4*)(src + off);
    ushort4 r; r.x=f2bf(v.x); r.y=f2bf(v.y); r.z=f2bf(v.z); r.w=f2bf(v.w);
    const int o = off >> 8, c = off & 255;
    *(ushort4*)(ws + (size_t)m*65536 + BL256(o, c)) = r;
    return;
  }

  const int hh = bid & 1;
  const int g = (bid >> 1) & 31;
  const int b = (bid >> 6) & 1;
  const int tsel = bid >> 7;
  const float* in = (tsel ? y : x) + ((size_t)b*CC + g*8)*S;
  unsigned short* outp = ws + (tsel ? OFF_NY : OFF_NX) + (size_t)b*S*CC;
  const int gk = (g >> 2) * 512;
  const int j = g & 3;
  const int posA = (j & 1)*16 + (j >> 1)*4;
  const int posB = posA + 8;
  const float* gamma = (tsel ? g2 : g1) + g*8;
  const float* beta  = (tsel ? b2 : b1) + g*8;

  const float* stats = (const float*)(ws + OFF_AO);
  const int unit = (tsel*2 + b)*32 + g;
  const float s  = stats[unit*4] + stats[unit*4 + 2];
  const float ssum = stats[unit*4 + 1] + stats[unit*4 + 3];
  const float invn = 1.0f/32768.0f;
  const float mean = s*invn;
  const float var  = ssum*invn - mean*mean;
  const float rstd = rsqrtf(var + 1e-6f);
  float sc[8], sh[8];
  #pragma unroll
  for (int ci = 0; ci < 8; ci++){ sc[ci] = rstd*gamma[ci]; sh[ci] = beta[ci] - mean*sc[ci]; }

  // vectorized apply over this half-unit: 8 ch x 2048 px
  #pragma unroll
  for (int i = 0; i < 2; i++){
    float4 v[8];
    #pragma unroll
    for (int ci = 0; ci < 8; ci++)
      v[ci] = ((const float4*)(in + (size_t)ci*S + hh*2048))[tid + i*256];
    const int p0 = hh*2048 + 4*(tid + i*256);
    const int base = ((p0 >> 4) << 12) + gk;
    #pragma unroll
    for (int jj = 0; jj < 4; jj++){
      const int p = p0 + jj;
      const int rowo = base + ((p & 15) << 5);
      float e0 = ((const float*)&v[0])[jj]*sc[0]+sh[0];
      float e1 = ((const float*)&v[1])[jj]*sc[1]+sh[1];
      float e2 = ((const float*)&v[2])[jj]*sc[2]+sh[2];
      float e3 = ((const float*)&v[3])[jj]*sc[3]+sh[3];
      float e4 = ((const float*)&v[4])[jj]*sc[4]+sh[4];
      float e5 = ((const float*)&v[5])[jj]*sc[5]+sh[5];
      float e6 = ((const float*)&v[6])[jj]*sc[6]+sh[6];
      float e7 = ((const float*)&v[7])[jj]*sc[7]+sh[7];
      ushort4 a0; a0.x=f2bf(e0); a0.y=f2bf(e1); a0.z=f2bf(e2); a0.w=f2bf(e3);
      ushort4 a1; a1.x=f2bf(e4); a1.y=f2bf(e5); a1.z=f2bf(e6); a1.w=f2bf(e7);
      *(ushort4*)(outp + rowo + posA) = a0;
      *(ushort4*)(outp + rowo + posB) = a1;
    }
  }
}

// ---------------- Q/K/V projection GEMMs, 768 blocks (3/CU) ----------------
// Epilogues stage results in a 16KB XOR-swizzled LDS tile, then write coalesced.
__global__ __launch_bounds__(256, 3) void qkv_gemm(unsigned short* __restrict__ ws,
    const float* __restrict__ bq, const float* __restrict__ bk, const float* __restrict__ bv)
{
  __shared__ unsigned short stg[8192];      // 16 KB epilogue staging
  const int tid = threadIdx.x;
  const int lane = tid & 63, wave = tid >> 6;
  const int lq = lane & 15, lg = lane >> 4;
  const int lofs = lq*32 + lg*8;
  const int bid = blockIdx.x;

  if (bid < 512){
    const int inst2 = bid >> 7;             // 0..3
    const int which = inst2 >> 1;           // 0=Q,1=K
    const int b = inst2 & 1;
    const int tile = bid & 127;
    const int mtile = tile & 3;             // == hd (64-aligned o-tile)
    const int ntile = tile >> 2;
    const int mbase = mtile*64 + (wave>>1)*32;
    const int nbase = ntile*128 + (wave&1)*64;
    const unsigned short* Amat = ws + (which==0 ? OFF_WQ : OFF_WK);
    const unsigned short* Bmat = ws + (which==0 ? OFF_NY : OFF_NX) + (size_t)b*S*CC;

    f32x4 acc[2][4];
    #pragma unroll
    for (int i = 0; i < 2; i++)
      #pragma unroll
      for (int j = 0; j < 4; j++)
        acc[i][j] = (f32x4){0.f,0.f,0.f,0.f};

    const unsigned short* Arow = Amat + (size_t)mbase*CC + lofs;
    const unsigned short* Brow = Bmat + (size_t)nbase*CC + lofs;
    for (int ks = 0; ks < CC; ks += 32) {
      bf16x8 af[2], bfr[4];
      #pragma unroll
      for (int mt = 0; mt < 2; mt++)
        af[mt] = *(const bf16x8*)(Arow + mt*16*CC + ks*16);
      #pragma unroll
      for (int nt = 0; nt < 4; nt++)
        bfr[nt] = *(const bf16x8*)(Brow + nt*16*CC + ks*16);
      #pragma unroll
      for (int mt = 0; mt < 2; mt++)
        #pragma unroll
        for (int nt = 0; nt < 4; nt++)
          acc[mt][nt] = MFMA16(af[mt], bfr[nt], acc[mt][nt]);
    }

    const float* bias = (which==0) ? bq : bk;
    const float scl = (which==0) ? 0.125f*1.44269504089f : 1.0f;
    unsigned short* Outp = ws + (which==0 ? OFF_Q : OFF_K) + (size_t)b*HH*S*DD;
    #pragma unroll
    for (int mt = 0; mt < 2; mt++){
      const int o = mbase + mt*16 + lg*4;
      const float4 bb = *(const float4*)(bias + o);
      const int db = KI(o & 63);
      #pragma unroll
      for (int nt = 0; nt < 4; nt++){
        const int lp = (wave&1)*64 + nt*16 + lq;
        f32x4 v = acc[mt][nt];
        ushort4 r;
        r.x = f2bf((v[0]+bb.x)*scl); r.y = f2bf((v[1]+bb.y)*scl);
        r.z = f2bf((v[2]+bb.z)*scl); r.w = f2bf((v[3]+bb.w)*scl);
        *(ushort4*)(stg + lp*64 + (db ^ ((lp & 7) << 3))) = r;
      }
    }
    __syncthreads();
    #pragma unroll
    for (int k = 0; k < 4; k++){
      const int c = tid + k*256;
      const int row = c >> 3, gl = (c & 7) << 3;
      uint4 v = *(const uint4*)(stg + row*64 + (gl ^ ((row & 7) << 3)));
      *(uint4*)(Outp + ((size_t)mtile*S + ntile*128 + row)*DD + gl) = v;
    }
  } else {
    const int r0 = bid - 512;
    const int b = r0 >> 7;
    const int tile = r0 & 127;
    const int mtile = tile >> 2;
    const int ntile = tile & 3;
    const int mbase = mtile*128 + (wave>>1)*64;
    const int nbase = ntile*64 + (wave&1)*32;
    const unsigned short* Amat = ws + OFF_NX + (size_t)b*S*CC;
    const unsigned short* Bmat = ws + OFF_WV;

    f32x4 acc[4][2];
    #pragma unroll
    for (int i = 0; i < 4; i++)
      #pragma unroll
      for (int j = 0; j < 2; j++)
        acc[i][j] = (f32x4){0.f,0.f,0.f,0.f};

    const unsigned short* Arow = Amat + (size_t)mbase*CC + lofs;
    const unsigned short* Brow = Bmat + (size_t)nbase*CC + lofs;
    for (int ks = 0; ks < CC; ks += 32) {
      bf16x8 af[4], bfr[2];
      #pragma unroll
      for (int mt = 0; mt < 4; mt++)
        af[mt] = *(const bf16x8*)(Arow + mt*16*CC + ks*16);
      #pragma unroll
      for (int nt = 0; nt < 2; nt++)
        bfr[nt] = *(const bf16x8*)(Brow + nt*16*CC + ks*16);
      #pragma unroll
      for (int mt = 0; mt < 4; mt++)
        #pragma unroll
        for (int nt = 0; nt < 2; nt++)
          acc[mt][nt] = MFMA16(af[mt], bfr[nt], acc[mt][nt]);
    }

    unsigned short* Outp = ws + OFF_V + (size_t)b*CC*S;
    #pragma unroll
    for (int nt = 0; nt < 2; nt++){
      const int o = nbase + nt*16 + lq;
      const int ro = o - ntile*64;
      const float bb = bv[o];
      #pragma unroll
      for (int mt = 0; mt < 4; mt++){
        const int lp = (wave>>1)*64 + mt*16 + lg*4;
        f32x4 v = acc[mt][nt];
        ushort4 r;
        r.x = f2bf(v[0]+bb); r.y = f2bf(v[1]+bb);
        r.z = f2bf(v[2]+bb); r.w = f2bf(v[3]+bb);
        *(ushort4*)(stg + ro*128 + (KI(lp) ^ ((ro & 7) << 3))) = r;
      }
    }
    __syncthreads();
    #pragma unroll
    for (int k = 0; k < 4; k++){
      const int c = tid + k*256;
      const int row = c >> 4, gl = (c & 15) << 3;
      uint4 v = *(const uint4*)(stg + row*128 + (gl ^ ((row & 7) << 3)));
      *(uint4*)(Outp + (size_t)(ntile*64 + row)*S + mtile*128 + gl) = v;
    }
  }
}

// ---------------- flash attention: 3-way split-t, 3 blocks/CU, VALU diet ----------------
// R12/R14-verbatim (runtime-cur double buffer -- the unrolled-template variant mis-schedules).
__global__ __launch_bounds__(256, 3) void attn_k(unsigned short* __restrict__ ws)
{
  __shared__ __align__(1024) char lds[32768];   // K: 0/8192, V: 16384/24576
  const int tid = threadIdx.x;
  const int lane = tid & 63, wave = tid >> 6;
  const int lq = lane & 15, lg = lane >> 4;
  const int rsw = (lq & 7) << 4;
  const int bid = blockIdx.x;
  const int bh = bid & 7;
  const int rest = bid >> 3;                // 0..95
  const int qblk = rest & 31;
  const int ch = rest >> 5;                 // 0..2
  const int tBeg = ch*1344 + (ch ? 64 : 0);
  const int tEnd = tBeg + 1344 + (ch ? 0 : 64);
  const unsigned short* Qp = ws + OFF_Q + (size_t)bh*S*DD;
  const unsigned short* Kp = ws + OFF_K + (size_t)bh*S*DD;
  const int b = bh >> 2, h = bh & 3;
  const unsigned short* Vp = ws + OFF_V + ((size_t)b*CC + h*DD)*S;
  const int qbw = qblk*128 + wave*32;

  bf16x8 qf[2][2];
  #pragma unroll
  for (int f = 0; f < 2; f++)
    #pragma unroll
    for (int hh = 0; hh < 2; hh++)
      qf[f][hh] = *(const bf16x8*)(Qp + (size_t)(qbw + f*16 + lq)*DD + hh*32 + lg*8);

  bf16x8 ones;
  #pragma unroll
  for (int i = 0; i < 8; i++) ones[i] = (__bf16)1.0f;

  const int csel = ((lane & 7) ^ ((lane >> 3) & 7)) * 8;
  const int srow = wave*16 + (lane >> 3);
  const int kofs0 = lq*128 + ((lg*16) ^ rsw);
  const int kofs1 = kofs0 ^ 64;

  f32x4 acc[4][2];
  #pragma unroll
  for (int i = 0; i < 4; i++)
    #pragma unroll
    for (int f = 0; f < 2; f++)
      acc[i][f] = (f32x4){0.f,0.f,0.f,0.f};
  f32x4 accL[2] = {(f32x4){0.f,0.f,0.f,0.f}, (f32x4){0.f,0.f,0.f,0.f}};
  float mr[2] = {-1e30f, -1e30f};

  #pragma unroll
  for (int j = 0; j < 2; j++){
    const int row = srow + j*8;
    GLOAD_LDS16(Kp + (size_t)(tBeg + row)*DD + csel, lds + wave*2048 + j*1024);
    GLOAD_LDS16(Vp + (size_t)row*S + tBeg + csel,    lds + 16384 + wave*2048 + j*1024);
  }
  __syncthreads();

  int cur = 0;
  for (int t0 = tBeg; t0 < tEnd; t0 += 64){
    const char* kb = lds + cur*8192;
    const char* vb = lds + 16384 + cur*8192;
    if (t0 + 64 < tEnd){
      char* kn = lds + (cur^1)*8192;
      char* vn = lds + 16384 + (cur^1)*8192;
      #pragma unroll
      for (int j = 0; j < 2; j++){
        const int row = srow + j*8;
        GLOAD_LDS16(Kp + (size_t)(t0 + 64 + row)*DD + csel, kn + wave*2048 + j*1024);
        GLOAD_LDS16(Vp + (size_t)row*S + (t0 + 64) + csel,  vn + wave*2048 + j*1024);
      }
    }
    bf16x8 kf[4][2];
    #pragma unroll
    for (int mt = 0; mt < 4; mt++){
      kf[mt][0] = *(const bf16x8*)(kb + mt*2048 + kofs0);
      kf[mt][1] = *(const bf16x8*)(kb + mt*2048 + kofs1);
    }
    f32x4 st[2][4];
    #pragma unroll
    for (int f = 0; f < 2; f++)
      #pragma unroll
      for (int mt = 0; mt < 4; mt++){
        f32x4 z = (f32x4){0.f,0.f,0.f,0.f};
        z = MFMA16(kf[mt][0], qf[f][0], z);
        z = MFMA16(kf[mt][1], qf[f][1], z);
        st[f][mt] = z;
      }
    bf16x8 vf[4][2];
    #pragma unroll
    for (int dt = 0; dt < 4; dt++){
      vf[dt][0] = *(const bf16x8*)(vb + dt*2048 + kofs0);
      vf[dt][1] = *(const bf16x8*)(vb + dt*2048 + kofs1);
    }
    // online softmax (exp2 domain), defer-max THR=8; max tree via v_max3
    float tmv[2];
    #pragma unroll
    for (int f = 0; f < 2; f++){
      float m1 = max3f(st[f][0][0], st[f][0][1], st[f][0][2]);
      float m2 = max3f(st[f][0][3], st[f][1][0], st[f][1][1]);
      float m3 = max3f(st[f][1][2], st[f][1][3], st[f][2][0]);
      float m4 = max3f(st[f][2][1], st[f][2][2], st[f][2][3]);
      float m5 = max3f(st[f][3][0], st[f][3][1], st[f][3][2]);
      float tm = fmaxf(fmaxf(max3f(m1, m2, m3), fmaxf(m4, m5)), st[f][3][3]);
      tm = fmaxf(tm, __shfl_xor(tm, 16));
      tm = fmaxf(tm, __shfl_xor(tm, 32));
      tmv[f] = tm;
    }
    if (!__all((tmv[0] <= mr[0] + 8.f) && (tmv[1] <= mr[1] + 8.f))){
      #pragma unroll
      for (int f = 0; f < 2; f++){
        const float mnew = fmaxf(mr[f], tmv[f]);
        const float c = __builtin_amdgcn_exp2f(mr[f] - mnew);
        #pragma unroll
        for (int dt = 0; dt < 4; dt++)
          #pragma unroll
          for (int r = 0; r < 4; r++)
            acc[dt][f][r] *= c;
        #pragma unroll
        for (int r = 0; r < 4; r++) accL[f][r] *= c;
        mr[f] = mnew;
      }
    }
    union PU { bf16x8 v; unsigned u[4]; } p0[2], p1[2];
    #pragma unroll
    for (int f = 0; f < 2; f++){
      #pragma unroll
      for (int mt = 0; mt < 4; mt++){
        float e0 = __builtin_amdgcn_exp2f(st[f][mt][0] - mr[f]);
        float e1 = __builtin_amdgcn_exp2f(st[f][mt][1] - mr[f]);
        float e2 = __builtin_amdgcn_exp2f(st[f][mt][2] - mr[f]);
        float e3 = __builtin_amdgcn_exp2f(st[f][mt][3] - mr[f]);
        if (mt < 2){ p0[f].u[mt*2] = cvtpk(e0, e1); p0[f].u[mt*2+1] = cvtpk(e2, e3); }
        else       { p1[f].u[(mt-2)*2] = cvtpk(e0, e1); p1[f].u[(mt-2)*2+1] = cvtpk(e2, e3); }
      }
    }
    // PV + l-sum (ones-A MFMA)
    #pragma unroll
    for (int dt = 0; dt < 4; dt++)
      #pragma unroll
      for (int f = 0; f < 2; f++){
        f32x4 a = acc[dt][f];
        a = MFMA16(vf[dt][0], p0[f].v, a);
        a = MFMA16(vf[dt][1], p1[f].v, a);
        acc[dt][f] = a;
      }
    #pragma unroll
    for (int f = 0; f < 2; f++){
      accL[f] = MFMA16(ones, p0[f].v, accL[f]);
      accL[f] = MFMA16(ones, p1[f].v, accL[f]);
    }
    __syncthreads();
    cur ^= 1;
  }

  // epilogue: unnormalized partials (PACC bf16) + m/l
  unsigned short* PA = pacc_base(ws, ch) + (size_t)bh*S*DD;
  float* ML = (float*)(ws + OFF_Q) + ((size_t)ch*8 + bh)*S*2;
  #pragma unroll
  for (int f = 0; f < 2; f++){
    const int q = qbw + f*16 + lq;
    #pragma unroll
    for (int dt = 0; dt < 4; dt++)
      *(ushort4*)(PA + (size_t)q*DD + dt*16 + lg*4) = pk4(acc[dt][f]);
    if (lg == 0){
      ML[(size_t)q*2]   = mr[f];
      ML[(size_t)q*2+1] = accL[f][0];
    }
  }
}

// ---------------- output projection: merge + GEMM + residual, 512 blocks (2/CU) ----------------
// tile 32q x 128o (PACC merged 2x); wave = 16q x 64o. R14-verbatim.
__global__ __launch_bounds__(256, 2) void outproj_k(unsigned short* __restrict__ ws,
    const float* __restrict__ bo, const float* __restrict__ x, float* __restrict__ out)
{
  __shared__ unsigned short ldsA[8192];     // 32 x 256 blocked, 16KB
  __shared__ float wtab[32][4][3];
  const int tid = threadIdx.x;
  const int lane = tid & 63, wave = tid >> 6;
  const int lq = lane & 15, lg = lane >> 4;
  const int lofs = lq*32 + lg*8;
  const int bid = blockIdx.x;
  const int b = bid >> 8;
  const int r0 = bid & 255;
  const int mtile = r0 >> 1;                // 128 q-tiles of 32
  const int ntile = r0 & 1;                 // 2 o-halves of 128
  const int qg = mtile*32;

  // phase 1: merge weights per (q,h)
  if (tid < 128){
    const int q = tid >> 2, h = tid & 3;
    const float* MLb = (const float*)(ws + OFF_Q);
    float m[3], l[3];
    #pragma unroll
    for (int c = 0; c < 3; c++){
      const float* p = MLb + (((size_t)c*8 + b*4 + h)*S + (qg + q))*2;
      m[c] = p[0]; l[c] = p[1];
    }
    const float M = fmaxf(m[0], fmaxf(m[1], m[2]));
    const float w0 = __builtin_amdgcn_exp2f(m[0] - M);
    const float w1 = __builtin_amdgcn_exp2f(m[1] - M);
    const float w2 = __builtin_amdgcn_exp2f(m[2] - M);
    const float inv = 1.0f / (w0*l[0] + w1*l[1] + w2*l[2]);
    wtab[q][h][0] = w0*inv; wtab[q][h][1] = w1*inv; wtab[q][h][2] = w2*inv;
  }
  __syncthreads();

  // phase 2: merge 32q x 256c into blocked LDS A-tile
  #pragma unroll
  for (int it = 0; it < 8; it++){
    const int w = it*256 + tid;
    const int q = w >> 6, cq = w & 63;
    const int h = cq >> 4, d = (cq & 15)*4;
    const size_t po = ((size_t)(b*4 + h)*S + (qg + q))*DD + d;
    const ushort4 a0 = *(const ushort4*)(ws + OFF_NY + po);
    const ushort4 a1 = *(const ushort4*)(ws + OFF_NX + po);
    const ushort4 a2 = *(const ushort4*)(ws + OFF_AO + po);
    const float w0 = wtab[q][h][0], w1 = wtab[q][h][1], w2 = wtab[q][h][2];
    f32x4 v;
    v[0] = bf2f(a0.x)*w0 + bf2f(a1.x)*w1 + bf2f(a2.x)*w2;
    v[1] = bf2f(a0.y)*w0 + bf2f(a1.y)*w1 + bf2f(a2.y)*w2;
    v[2] = bf2f(a0.z)*w0 + bf2f(a1.z)*w1 + bf2f(a2.z)*w2;
    v[3] = bf2f(a0.w)*w0 + bf2f(a1.w)*w1 + bf2f(a2.w)*w2;
    *(ushort4*)(ldsA + BL256(q, cq*4)) = pk4(v);
  }
  __syncthreads();

  // phase 3: GEMM 32q x 128o (A from LDS, B=WO from global) + bias + residual
  const int mf = wave & 1;                  // 2 m-frags of 16 q
  const int nb = ntile*128 + (wave >> 1)*64;
  f32x4 acc[4];
  #pragma unroll
  for (int i = 0; i < 4; i++) acc[i] = (f32x4){0.f,0.f,0.f,0.f};
  const unsigned short* Arow = ldsA + mf*16*CC + lofs;
  const unsigned short* Brow = ws + OFF_WO + (size_t)nb*CC + lofs;
  for (int ks = 0; ks < CC; ks += 32) {
    bf16x8 af = *(const bf16x8*)(Arow + ks*16);
    bf16x8 bfr[4];
    #pragma unroll
    for (int nt = 0; nt < 4; nt++)
      bfr[nt] = *(const bf16x8*)(Brow + nt*16*CC + ks*16);
    #pragma unroll
    for (int nt = 0; nt < 4; nt++)
      acc[nt] = MFMA16(af, bfr[nt], acc[nt]);
  }
  #pragma unroll
  for (int nt = 0; nt < 4; nt++){
    const int o = nb + nt*16 + lq;
    const float bb = bo[o];
    const int p = qg + mf*16 + lg*4;
    const size_t idx = ((size_t)b*CC + o)*S + p;
    const float4 xr = *(const float4*)(x + idx);
    f32x4 v = acc[nt];
    float4 r; r.x = v[0]+bb+xr.x; r.y = v[1]+bb+xr.y; r.z = v[2]+bb+xr.z; r.w = v[3]+bb+xr.w;
    *(float4*)(out + idx) = r;
  }
}

extern "C" void kernel_launch(void* const* d_in, const int* in_sizes, int n_in,
                              void* d_out, int out_size, void* d_ws, size_t ws_size,
                              hipStream_t stream) {
  const float* x  = (const float*)d_in[0];
  const float* y  = (const float*)d_in[1];
  const float* g1 = (const float*)d_in[2];
  const float* b1 = (const float*)d_in[3];
  const float* g2 = (const float*)d_in[4];
  const float* b2 = (const float*)d_in[5];
  const float* wq = (const float*)d_in[6];
  const float* bq = (const float*)d_in[7];
  const float* wk = (const float*)d_in[8];
  const float* bk = (const float*)d_in[9];
  const float* wv = (const float*)d_in[10];
  const float* bv = (const float*)d_in[11];
  const float* wo = (const float*)d_in[12];
  const float* bo = (const float*)d_in[13];
  float* out = (float*)d_out;
  unsigned short* ws16 = (unsigned short*)d_ws;

  stats_k  <<<256, 256, 0, stream>>>(x, y, ws16);
  apply_k  <<<512, 256, 0, stream>>>(x, y, g1, b1, g2, b2, wq, wk, wv, wo, ws16);
  qkv_gemm <<<768, 256, 0, stream>>>(ws16, bq, bk, bv);
  attn_k   <<<768, 256, 0, stream>>>(ws16);
  outproj_k<<<512, 256, 0, stream>>>(ws16, bo, x, out);
}